// Round 1
// baseline (2371.539 us; speedup 1.0000x reference)
//
#include <hip/hip_runtime.h>
#include <hip/hip_fp16.h>

#define T_LEN 1024
#define E_DIM 300
#define H_DIM 512
#define D_DIM 1024
#define K_TAGS 12
#define G4 2048   // 4*H

typedef __attribute__((ext_vector_type(8))) short short8x;  // 8 bf16
typedef __attribute__((ext_vector_type(4))) float f32x4;

static __device__ __forceinline__ float frcp(float x){ return __builtin_amdgcn_rcpf(x); }
static __device__ __forceinline__ float sigm(float x){ return frcp(1.f + __expf(-x)); }
// overflow-safe fast tanh
static __device__ __forceinline__ float ftanh(float x){
  const float e = __expf(2.f * fabsf(x));
  const float t = 1.f - 2.f * frcp(e + 1.f);
  return copysignf(t, x);
}
// f32 -> bf16 round-to-nearest-even
static __device__ __forceinline__ unsigned short f2b(float f){
  unsigned u = __float_as_uint(f);
  return (unsigned short)((u + 0x7fffu + ((u >> 16) & 1u)) >> 16);
}
static __device__ __forceinline__ uint4 pack8(const float* s){
  uint4 o;
  o.x = (unsigned)f2b(s[0]) | ((unsigned)f2b(s[1]) << 16);
  o.y = (unsigned)f2b(s[2]) | ((unsigned)f2b(s[3]) << 16);
  o.z = (unsigned)f2b(s[4]) | ((unsigned)f2b(s[5]) << 16);
  o.w = (unsigned)f2b(s[6]) | ((unsigned)f2b(s[7]) << 16);
  return o;
}

// ---------------- gather: x[t,e] = word_embeds[sentence[t], e] ----------------
__global__ void k_gather(const int* __restrict__ sent, const float* __restrict__ we,
                         float* __restrict__ x){
  int idx = blockIdx.x*256 + threadIdx.x;
  if (idx < T_LEN*E_DIM){
    int t = idx / E_DIM, e = idx - t*E_DIM;
    x[idx] = we[(size_t)sent[t]*E_DIM + e];
  }
}

// ---------------- zero the tagged h ring buffer (2 dir * 2 slot * 512 u32) ----
__global__ void k_init(unsigned* __restrict__ hbuf){
  int i = blockIdx.x*256 + threadIdx.x;
  if (i < 2048) hbuf[i] = 0u;  // tag 0, bf16 value +0.0
}

// ---------------- MFMA bf16 GEMM: C = act( A(·rev?) * B^T + bias ) ------------
// (unchanged — verified)
__global__ __launch_bounds__(256) void k_gemm_mfma(
    const float* __restrict__ Af, int lda, int arev,
    const float* __restrict__ Bf, const unsigned short* __restrict__ Bh, int ldb,
    const float* __restrict__ bias, int act,
    float* __restrict__ C, int ldc, int M, int N, int K)
{
  __shared__ __align__(16) unsigned short As[64*40];
  __shared__ __align__(16) unsigned short Bs[64*40];
  const int tid = threadIdx.x;
  const int bm = blockIdx.y*64, bn = blockIdx.x*64;
  const int r  = tid >> 2, c8 = (tid & 3) * 8;
  const int wave = tid >> 6, lane = tid & 63;
  const int wm = (wave >> 1) * 32, wn = (wave & 1) * 32;
  const int col = lane & 15, quad = lane >> 4;

  const int am = arev ? (M-1-(bm+r)) : (bm+r);
  const float* arow = Af + (size_t)am*lda;
  const float* brow = Bf ? (Bf + (size_t)(bn+r)*ldb) : (const float*)0;
  const unsigned short* brh = Bh ? (Bh + (size_t)(bn+r)*ldb) : (const unsigned short*)0;

  uint4* aw = (uint4*)(As + r*40 + c8);
  uint4* bw = (uint4*)(Bs + r*40 + c8);

  f32x4 acc[2][2];
  #pragma unroll
  for (int i=0;i<2;i++)
    #pragma unroll
    for (int j=0;j<2;j++) acc[i][j] = (f32x4){0.f,0.f,0.f,0.f};

  for (int k0 = 0; k0 < K; k0 += 32){
    uint4 avv, bvv;
    if (k0 + 32 <= K){
      avv = pack8(arow + k0 + c8);
      bvv = Bh ? *(const uint4*)(brh + k0 + c8) : pack8(brow + k0 + c8);
    } else {
      float ta[8], tb[8];
      #pragma unroll
      for (int i=0;i<8;i++){
        const int kk = k0 + c8 + i;
        ta[i] = (kk < K) ? arow[kk] : 0.f;
        tb[i] = (kk < K && Bf) ? brow[kk] : 0.f;
      }
      avv = pack8(ta); bvv = pack8(tb);
    }
    if (k0) __syncthreads();
    *aw = avv; *bw = bvv;
    __syncthreads();
    const short8x a0 = *(const short8x*)(As + (wm+col)*40    + quad*8);
    const short8x a1 = *(const short8x*)(As + (wm+16+col)*40 + quad*8);
    const short8x b0 = *(const short8x*)(Bs + (wn+col)*40    + quad*8);
    const short8x b1 = *(const short8x*)(Bs + (wn+16+col)*40 + quad*8);
    acc[0][0] = __builtin_amdgcn_mfma_f32_16x16x32_bf16(a0, b0, acc[0][0], 0, 0, 0);
    acc[0][1] = __builtin_amdgcn_mfma_f32_16x16x32_bf16(a0, b1, acc[0][1], 0, 0, 0);
    acc[1][0] = __builtin_amdgcn_mfma_f32_16x16x32_bf16(a1, b0, acc[1][0], 0, 0, 0);
    acc[1][1] = __builtin_amdgcn_mfma_f32_16x16x32_bf16(a1, b1, acc[1][1], 0, 0, 0);
  }

  #pragma unroll
  for (int mt=0;mt<2;mt++){
    #pragma unroll
    for (int nt=0;nt<2;nt++){
      const int cc = bn + wn + 16*nt + col;
      const float bs = bias ? bias[cc] : 0.f;
      #pragma unroll
      for (int i=0;i<4;i++){
        const int rr = bm + wm + 16*mt + quad*4 + i;
        float v = acc[mt][nt][i] + bs;
        if (act) v = ftanh(v);
        C[(size_t)rr*ldc + cc] = v;
      }
    }
  }
}

// ---------------- persistent bidirectional LSTM recurrence (MFMA) -------------
// 64 WGs x 256 threads. blocks 0..31: forward, 32..63: backward.
// WG w owns h-units [w*16, w*16+16); wave g (0..3) computes gate g's 16 rows
// as one 16-row MFMA tile over K=512 with weights preloaded in VGPRs.
//
// Round-4 restructure (latency attack — the step is coherence-round-trip bound):
//  * ONLY WAVE 0 POLLS: 64 lanes x 8 coalesced words (2-line requests/instr)
//    -> 16 line-requests/WG/iter instead of 64; 4x less pressure on the 16
//    hot L3 lines every poller hammers.
//  * h published as (tag<<16)|bf16 — the only consumer is the bf16 MFMA B
//    operand, so the f16->f32->bf16 decode on the critical path becomes a mask.
//  * 2 barriers/step instead of 3 (end-of-loop barrier proven redundant:
//    waves 1-3's lds_hb reads retire before the post-raw barrier, and only
//    wave 0 touches lds_hb/raw after it).
//  * xg prefetch hoisted ABOVE the poll: ~1500 cy of cover instead of ~400.
__global__ __launch_bounds__(256, 1) void k_lstm(
    const float* __restrict__ Whh_f, const float* __restrict__ Whh_b,
    const float* __restrict__ bih_f, const float* __restrict__ bhh_f,
    const float* __restrict__ bih_b, const float* __restrict__ bhh_b,
    const float* __restrict__ xg_f, const float* __restrict__ xg_b,
    unsigned* __restrict__ hbuf, float* __restrict__ enc)
{
  const int dir = blockIdx.x >> 5;
  const int w   = blockIdx.x & 31;
  const int tid = threadIdx.x;
  const int wave = tid >> 6, lane = tid & 63;
  const int col = lane & 15, quad = lane >> 4;

  const float* Whh = dir ? Whh_b : Whh_f;
  const float* xg  = dir ? xg_b  : xg_f;

  // ---- A-frag preload: wave 'wave' = gate, rows rowA = gate*512 + w*16 + col
  const int rowA = wave*H_DIM + w*16 + col;
  short8x w_frag[16];
  #pragma unroll
  for (int s=0;s<16;s++){
    const float* bp = Whh + (size_t)rowA*H_DIM + s*32 + quad*8;
    uint4 u = pack8(bp);
    w_frag[s] = *reinterpret_cast<short8x*>(&u);
  }

  // ---- wave-0 per-gate-value state (tid<64): bias, xg pipeline
  float bias_r = 0.f, xg_cur = 0.f, c_reg = 0.f;
  int row2 = 0;
  if (tid < 64){
    row2 = (tid >> 4)*H_DIM + w*16 + (tid & 15);
    bias_r = dir ? (bih_b[row2] + bhh_b[row2]) : (bih_f[row2] + bhh_f[row2]);
    xg_cur = xg[row2];              // step t=1 uses xg row 0
  }

  __shared__ __align__(16) unsigned short lds_hb[512];  // h_{t-1} as bf16
  __shared__ __align__(16) float raw[64];               // gate pre-activations

  unsigned* hb = hbuf + dir*1024;  // [2][512]

  for (int t = 1; t <= T_LEN; ++t){
    // ---- wave 0: prefetch next xg, then poll + stage h_{t-1}
    float xg_nxt = 0.f;
    if (tid < 64){
      if (t < T_LEN) xg_nxt = xg[(size_t)t*G4 + row2];  // covered by poll stall

      unsigned* s0 = hb + ((t-1)&1)*512 + tid;
      const unsigned want = (unsigned)(t-1);
      unsigned v[8];
      for (;;){
        #pragma unroll
        for (int i=0;i<8;i++)
          v[i] = __hip_atomic_load(s0 + i*64, __ATOMIC_RELAXED, __HIP_MEMORY_SCOPE_AGENT);
        bool ok = true;
        #pragma unroll
        for (int i=0;i<8;i++) ok &= ((v[i] >> 16) == want);
        if (__all(ok)) break;
      }
      #pragma unroll
      for (int i=0;i<8;i++) lds_hb[i*64 + tid] = (unsigned short)(v[i] & 0xffffu);
    }
    __syncthreads();  // A: lds_hb ready

    // ---- matvec: 16 chained-by-2 MFMAs, B = h broadcast-replicated
    f32x4 a0 = (f32x4){0.f,0.f,0.f,0.f}, a1 = (f32x4){0.f,0.f,0.f,0.f};
    #pragma unroll
    for (int s=0;s<16;s+=2){
      const short8x b0 = *(const short8x*)(lds_hb + s*32     + quad*8);
      const short8x b1 = *(const short8x*)(lds_hb + (s+1)*32 + quad*8);
      a0 = __builtin_amdgcn_mfma_f32_16x16x32_bf16(w_frag[s],   b0, a0, 0, 0, 0);
      a1 = __builtin_amdgcn_mfma_f32_16x16x32_bf16(w_frag[s+1], b1, a1, 0, 0, 0);
    }
    if (col == 0){
      f32x4 asum = a0 + a1;   // D[m] in regs i: m = quad*4+i (same for all cols)
      *reinterpret_cast<f32x4*>(raw + wave*16 + quad*4) = asum;
    }
    __syncthreads();  // B: raw ready

    // ---- gates + state update, all inside wave 0 (shfl handoff, no barrier)
    if (tid < 64){
      float v = raw[tid] + bias_r + xg_cur;
      const float va = ((tid >> 4) == 2) ? ftanh(v) : sigm(v);
      const int l2 = tid & 15;
      const float iv = __shfl(va, l2);
      const float fv = __shfl(va, l2 + 16);
      const float gg = __shfl(va, l2 + 32);
      const float ov = __shfl(va, l2 + 48);
      if (tid < 16){
        c_reg = fv*c_reg + iv*gg;
        const float hh = ov*ftanh(c_reg);
        const int hj = w*16 + tid;
        // publish FIRST (what other WGs wait on) — bf16 payload
        const unsigned hv = ((unsigned)t << 16) | (unsigned)f2b(hh);
        __hip_atomic_store(hb + (t&1)*512 + hj, hv,
                           __ATOMIC_RELAXED, __HIP_MEMORY_SCOPE_AGENT);
        const int tt = dir ? (T_LEN - t) : (t - 1);
        enc[(size_t)tt*D_DIM + dir*H_DIM + hj] = hh;
      }
      xg_cur = xg_nxt;
    }
    // no barrier C: waves 1-3 park at barrier A of the next iteration; their
    // lds_hb reads retired before barrier B, and only wave 0 writes lds_hb/raw
    // between B(t) and A(t+1).
  }
}

// ---------------- row softmax in place, rows of 1024 --------------------------
__global__ __launch_bounds__(256) void k_softmax(float* __restrict__ S){
  float* r = S + (size_t)blockIdx.x*1024;
  const int tid = threadIdx.x;
  float v[4];
  #pragma unroll
  for (int i=0;i<4;i++) v[i] = r[tid + i*256];
  float m = fmaxf(fmaxf(v[0],v[1]), fmaxf(v[2],v[3]));
  #pragma unroll
  for (int off=32; off>=1; off>>=1) m = fmaxf(m, __shfl_xor(m, off));
  __shared__ float red[4], red2[4];
  const int wid = tid >> 6, lane = tid & 63;
  if (lane == 0) red[wid] = m;
  __syncthreads();
  m = fmaxf(fmaxf(red[0],red[1]), fmaxf(red[2],red[3]));
  float s = 0.f;
  #pragma unroll
  for (int i=0;i<4;i++){ v[i] = __expf(v[i]-m); s += v[i]; }
  #pragma unroll
  for (int off=32; off>=1; off>>=1) s += __shfl_xor(s, off);
  if (lane == 0) red2[wid] = s;
  __syncthreads();
  s = red2[0]+red2[1]+red2[2]+red2[3];
  const float inv = frcp(s);
  #pragma unroll
  for (int i=0;i<4;i++) r[tid + i*256] = v[i]*inv;
}

// ---------------- copy enc into cat[:, 0:1024] (f32) --------------------------
__global__ void k_copy_enc(const float* __restrict__ enc, float* __restrict__ cat){
  int idx = blockIdx.x*256 + threadIdx.x;
  if (idx < T_LEN*D_DIM){
    int t = idx >> 10, d = idx & 1023;
    cat[(size_t)t*2048 + d] = enc[idx];
  }
}

// ---------------- transpose-cast: encT_bf16[d][t] = bf16(enc[t][d]) -----------
__global__ __launch_bounds__(256) void k_castT(const float* __restrict__ src,
                                               unsigned short* __restrict__ dst){
  __shared__ float tile[32][33];
  const int bx = blockIdx.x*32, by = blockIdx.y*32;
  const int tx = threadIdx.x & 31, ty8 = threadIdx.x >> 5;
  #pragma unroll
  for (int i=ty8;i<32;i+=8) tile[i][tx] = src[(size_t)(by+i)*1024 + bx+tx];
  __syncthreads();
  #pragma unroll
  for (int i=ty8;i<32;i+=8) dst[(size_t)(bx+i)*1024 + by+tx] = f2b(tile[tx][i]);
}

// ---------------- feats = h1 * tag_W^T + tag_b  [1024,12] ---------------------
__global__ __launch_bounds__(256) void k_feats(
    const float* __restrict__ h1, const float* __restrict__ tagW,
    const float* __restrict__ tagb, float* __restrict__ feats)
{
  const int t = blockIdx.x;
  const int wave = threadIdx.x >> 6, lane = threadIdx.x & 63;
  const float* hr = h1 + (size_t)t*D_DIM;
  float hv[16];
  #pragma unroll
  for (int i=0;i<16;i++) hv[i] = hr[lane + 64*i];
  #pragma unroll
  for (int j=0;j<3;j++){
    const int tag = wave*3 + j;
    const float* wr = tagW + (size_t)tag*D_DIM;
    float s = 0.f;
    #pragma unroll
    for (int i=0;i<16;i++) s += hv[i]*wr[lane + 64*i];
    #pragma unroll
    for (int off=32; off>=1; off>>=1) s += __shfl_xor(s, off);
    if (lane == 0) feats[(size_t)t*K_TAGS + tag] = s + tagb[tag];
  }
}

// ---------------- CRF forward + gold score, single wave -----------------------
__global__ void k_crf(const float* __restrict__ feats, const float* __restrict__ trans,
                      const int* __restrict__ tags, float* __restrict__ out){
  const int tid = threadIdx.x;  // 64 threads, one wave
  float gold = 0.f;
  for (int i = tid; i <= T_LEN; i += 64){
    const int to = (i < T_LEN) ? tags[i]   : 11;        // STOP
    const int fr = (i == 0)    ? 10        : tags[i-1]; // START
    gold += trans[to*K_TAGS + fr];
    if (i < T_LEN) gold += feats[(size_t)i*K_TAGS + tags[i]];
  }
  #pragma unroll
  for (int off=32; off>=1; off>>=1) gold += __shfl_xor(gold, off);

  float Trow[K_TAGS];
  if (tid < K_TAGS){
    #pragma unroll
    for (int j=0;j<K_TAGS;j++) Trow[j] = trans[tid*K_TAGS + j];
  }
  float alpha = (tid == 10) ? 0.f : -10000.f;
  for (int t=0;t<T_LEN;++t){
    float av[K_TAGS];
    #pragma unroll
    for (int j=0;j<K_TAGS;j++) av[j] = __shfl(alpha, j);
    if (tid < K_TAGS){
      float vv[K_TAGS], m = -1e30f;
      #pragma unroll
      for (int j=0;j<K_TAGS;j++){ vv[j] = av[j] + Trow[j]; m = fmaxf(m, vv[j]); }
      float s = 0.f;
      #pragma unroll
      for (int j=0;j<K_TAGS;j++) s += __expf(vv[j]-m);
      alpha = m + __logf(s) + feats[(size_t)t*K_TAGS + tid];
    }
  }
  float v = (tid < K_TAGS) ? (alpha + trans[11*K_TAGS + tid]) : -1e30f;
  float m = v;
  #pragma unroll
  for (int off=32; off>=1; off>>=1) m = fmaxf(m, __shfl_xor(m, off));
  float e = (tid < K_TAGS) ? __expf(v - m) : 0.f;
  #pragma unroll
  for (int off=32; off>=1; off>>=1) e += __shfl_xor(e, off);
  if (tid == 0) out[0] = (m + __logf(e)) - gold;
}

// ------------------------------------------------------------------------------
extern "C" void kernel_launch(void* const* d_in, const int* in_sizes, int n_in,
                              void* d_out, int out_size, void* d_ws, size_t ws_size,
                              hipStream_t stream)
{
  const int*   sentence = (const int*)d_in[0];
  const int*   tags     = (const int*)d_in[1];
  const float* we       = (const float*)d_in[2];
  const float* Wih_f    = (const float*)d_in[3];
  const float* Whh_f    = (const float*)d_in[4];
  const float* bih_f    = (const float*)d_in[5];
  const float* bhh_f    = (const float*)d_in[6];
  const float* Wih_b    = (const float*)d_in[7];
  const float* Whh_b    = (const float*)d_in[8];
  const float* bih_b    = (const float*)d_in[9];
  const float* bhh_b    = (const float*)d_in[10];
  const float* attn_W   = (const float*)d_in[11];
  const float* attn_b   = (const float*)d_in[12];
  const float* h2h1_W   = (const float*)d_in[13];
  const float* h2h1_b   = (const float*)d_in[14];
  const float* tag_W    = (const float*)d_in[15];
  const float* tag_b    = (const float*)d_in[16];
  const float* trans    = (const float*)d_in[17];
  float* out = (float*)d_out;

  // workspace layout (floats) — identical footprint to the proven pool
  float* ws     = (float*)d_ws;
  float* cat    = ws;                  // [1024,2048]   also xg_f
  float* reg2   = cat  + 2097152;      // [2M]          xg_b; later scores+h1
  float* enc    = reg2 + 2097152;      // [1024,1024]
  float* proj   = enc  + 1048576;      // [1024,1024]   also x; later encT_bf16
  float* feats  = proj + 1048576;      // [1024,12]
  unsigned* hbuf= (unsigned*)(feats + 12288);  // 2048 u32
  float* xg_f   = cat;
  float* xg_b   = reg2;
  float* scores = reg2;
  float* h1     = reg2 + 1048576;
  float* x      = proj;
  unsigned short* encT = (unsigned short*)proj;  // 2 MiB, used after proj dead

  // 1. gather embeddings
  k_gather<<<dim3((T_LEN*E_DIM + 255)/256), dim3(256), 0, stream>>>(sentence, we, x);
  // 2. init h ring buffer
  k_init<<<dim3(8), dim3(256), 0, stream>>>(hbuf);
  // 3. xg_f = x * Wih_f^T        [1024,2048], K=300 ragged
  k_gemm_mfma<<<dim3(32,16), dim3(256), 0, stream>>>(x, E_DIM, 0,
      Wih_f, nullptr, E_DIM, nullptr, 0, xg_f, G4, T_LEN, G4, E_DIM);
  // 4. xg_b = rev(x) * Wih_b^T   [1024,2048]
  k_gemm_mfma<<<dim3(32,16), dim3(256), 0, stream>>>(x, E_DIM, 1,
      Wih_b, nullptr, E_DIM, nullptr, 0, xg_b, G4, T_LEN, G4, E_DIM);
  // 5. bidirectional recurrence -> enc [1024,1024]  (MFMA matvec, 64 WGs)
  k_lstm<<<dim3(64), dim3(256), 0, stream>>>(Whh_f, Whh_b, bih_f, bhh_f,
      bih_b, bhh_b, xg_f, xg_b, hbuf, enc);
  // 6. proj = enc * attn_W^T + attn_b
  k_gemm_mfma<<<dim3(16,16), dim3(256), 0, stream>>>(enc, D_DIM, 0,
      attn_W, nullptr, D_DIM, attn_b, 0, proj, D_DIM, T_LEN, D_DIM, D_DIM);
  // 7. scores = enc * proj^T
  k_gemm_mfma<<<dim3(16,16), dim3(256), 0, stream>>>(enc, D_DIM, 0,
      proj, nullptr, D_DIM, nullptr, 0, scores, T_LEN, T_LEN, T_LEN, D_DIM);
  // 8. row softmax in place
  k_softmax<<<dim3(1024), dim3(256), 0, stream>>>(scores);
  // 9. cat[:, :1024] = enc   (f32)
  k_copy_enc<<<dim3(4096), dim3(256), 0, stream>>>(enc, cat);
  // 10. encT_bf16 = enc^T    (proj region is dead now)
  k_castT<<<dim3(32,32), dim3(256), 0, stream>>>(enc, encT);
  // 11. cat[:, 1024:] = w * enc  via A=w, B=encT (bf16 precast)
  k_gemm_mfma<<<dim3(16,16), dim3(256), 0, stream>>>(scores, T_LEN, 0,
      nullptr, encT, D_DIM, nullptr, 0, cat + 1024, 2048, T_LEN, D_DIM, T_LEN);
  // 12. h1 = tanh(cat * h2h1_W^T + h2h1_b), K=2048
  k_gemm_mfma<<<dim3(16,16), dim3(256), 0, stream>>>(cat, 2048, 0,
      h2h1_W, nullptr, 2048, h2h1_b, 1, h1, D_DIM, T_LEN, D_DIM, 2048);
  // 13. feats = h1 * tag_W^T + tag_b   [1024,12]
  k_feats<<<dim3(1024), dim3(256), 0, stream>>>(h1, tag_W, tag_b, feats);
  // 14. CRF NLL
  k_crf<<<dim3(1), dim3(64), 0, stream>>>(feats, trans, tags, out);
}

// Round 2
// 2325.210 us; speedup vs baseline: 1.0199x; 1.0199x over previous
//
#include <hip/hip_runtime.h>
#include <hip/hip_fp16.h>

#define T_LEN 1024
#define E_DIM 300
#define H_DIM 512
#define D_DIM 1024
#define K_TAGS 12
#define G4 2048   // 4*H

typedef __attribute__((ext_vector_type(8))) short short8x;  // 8 bf16
typedef __attribute__((ext_vector_type(4))) float f32x4;

static __device__ __forceinline__ float frcp(float x){ return __builtin_amdgcn_rcpf(x); }
static __device__ __forceinline__ float sigm(float x){ return frcp(1.f + __expf(-x)); }
// overflow-safe fast tanh
static __device__ __forceinline__ float ftanh(float x){
  const float e = __expf(2.f * fabsf(x));
  const float t = 1.f - 2.f * frcp(e + 1.f);
  return copysignf(t, x);
}
// f32 -> bf16 round-to-nearest-even
static __device__ __forceinline__ unsigned short f2b(float f){
  unsigned u = __float_as_uint(f);
  return (unsigned short)((u + 0x7fffu + ((u >> 16) & 1u)) >> 16);
}
static __device__ __forceinline__ uint4 pack8(const float* s){
  uint4 o;
  o.x = (unsigned)f2b(s[0]) | ((unsigned)f2b(s[1]) << 16);
  o.y = (unsigned)f2b(s[2]) | ((unsigned)f2b(s[3]) << 16);
  o.z = (unsigned)f2b(s[4]) | ((unsigned)f2b(s[5]) << 16);
  o.w = (unsigned)f2b(s[6]) | ((unsigned)f2b(s[7]) << 16);
  return o;
}

// ---------------- gather: x[t,e] = word_embeds[sentence[t], e] ----------------
__global__ void k_gather(const int* __restrict__ sent, const float* __restrict__ we,
                         float* __restrict__ x){
  int idx = blockIdx.x*256 + threadIdx.x;
  if (idx < T_LEN*E_DIM){
    int t = idx / E_DIM, e = idx - t*E_DIM;
    x[idx] = we[(size_t)sent[t]*E_DIM + e];
  }
}

// ---------------- zero the tagged h ring buffer (2 dir * 2 slot * 512 u32) ----
__global__ void k_init(unsigned* __restrict__ hbuf){
  int i = blockIdx.x*256 + threadIdx.x;
  if (i < 2048) hbuf[i] = 0u;  // tag 0, bf16 value +0.0
}

// ---------------- MFMA bf16 GEMM: C = act( A(·rev?) * B^T + bias ) ------------
// (unchanged — verified)
__global__ __launch_bounds__(256) void k_gemm_mfma(
    const float* __restrict__ Af, int lda, int arev,
    const float* __restrict__ Bf, const unsigned short* __restrict__ Bh, int ldb,
    const float* __restrict__ bias, int act,
    float* __restrict__ C, int ldc, int M, int N, int K)
{
  __shared__ __align__(16) unsigned short As[64*40];
  __shared__ __align__(16) unsigned short Bs[64*40];
  const int tid = threadIdx.x;
  const int bm = blockIdx.y*64, bn = blockIdx.x*64;
  const int r  = tid >> 2, c8 = (tid & 3) * 8;
  const int wave = tid >> 6, lane = tid & 63;
  const int wm = (wave >> 1) * 32, wn = (wave & 1) * 32;
  const int col = lane & 15, quad = lane >> 4;

  const int am = arev ? (M-1-(bm+r)) : (bm+r);
  const float* arow = Af + (size_t)am*lda;
  const float* brow = Bf ? (Bf + (size_t)(bn+r)*ldb) : (const float*)0;
  const unsigned short* brh = Bh ? (Bh + (size_t)(bn+r)*ldb) : (const unsigned short*)0;

  uint4* aw = (uint4*)(As + r*40 + c8);
  uint4* bw = (uint4*)(Bs + r*40 + c8);

  f32x4 acc[2][2];
  #pragma unroll
  for (int i=0;i<2;i++)
    #pragma unroll
    for (int j=0;j<2;j++) acc[i][j] = (f32x4){0.f,0.f,0.f,0.f};

  for (int k0 = 0; k0 < K; k0 += 32){
    uint4 avv, bvv;
    if (k0 + 32 <= K){
      avv = pack8(arow + k0 + c8);
      bvv = Bh ? *(const uint4*)(brh + k0 + c8) : pack8(brow + k0 + c8);
    } else {
      float ta[8], tb[8];
      #pragma unroll
      for (int i=0;i<8;i++){
        const int kk = k0 + c8 + i;
        ta[i] = (kk < K) ? arow[kk] : 0.f;
        tb[i] = (kk < K && Bf) ? brow[kk] : 0.f;
      }
      avv = pack8(ta); bvv = pack8(tb);
    }
    if (k0) __syncthreads();
    *aw = avv; *bw = bvv;
    __syncthreads();
    const short8x a0 = *(const short8x*)(As + (wm+col)*40    + quad*8);
    const short8x a1 = *(const short8x*)(As + (wm+16+col)*40 + quad*8);
    const short8x b0 = *(const short8x*)(Bs + (wn+col)*40    + quad*8);
    const short8x b1 = *(const short8x*)(Bs + (wn+16+col)*40 + quad*8);
    acc[0][0] = __builtin_amdgcn_mfma_f32_16x16x32_bf16(a0, b0, acc[0][0], 0, 0, 0);
    acc[0][1] = __builtin_amdgcn_mfma_f32_16x16x32_bf16(a0, b1, acc[0][1], 0, 0, 0);
    acc[1][0] = __builtin_amdgcn_mfma_f32_16x16x32_bf16(a1, b0, acc[1][0], 0, 0, 0);
    acc[1][1] = __builtin_amdgcn_mfma_f32_16x16x32_bf16(a1, b1, acc[1][1], 0, 0, 0);
  }

  #pragma unroll
  for (int mt=0;mt<2;mt++){
    #pragma unroll
    for (int nt=0;nt<2;nt++){
      const int cc = bn + wn + 16*nt + col;
      const float bs = bias ? bias[cc] : 0.f;
      #pragma unroll
      for (int i=0;i<4;i++){
        const int rr = bm + wm + 16*mt + quad*4 + i;
        float v = acc[mt][nt][i] + bs;
        if (act) v = ftanh(v);
        C[(size_t)rr*ldc + cc] = v;
      }
    }
  }
}

// ---------------- persistent bidirectional LSTM recurrence (MFMA) -------------
// 64 WGs x 256 threads. blocks 0..31: forward, 32..63: backward.
// WG w owns h-units [w*16, w*16+16); wave g computes gate g's 16 rows.
//
// Round-2 re-phase (post-mortem of round-1 regression):
//  * Poll semantics reverted to the PROVEN per-thread-exit form (round-1's
//    __all() over 8 words coarsened detection and cost 14%).
//  * Loop re-phased so gates(t-1)+publish (wave 0) run CONCURRENTLY with
//    polling for tag t-1 (waves 2-3, 124 threads x 4 consecutive words).
//    The agent-scope round trip R now overlaps the ~250cy gate chain.
//  * Wave 0 stages its OWN 16 h values directly to LDS; pollers skip the
//    own-WG range (no global round trip for local data).
//  * 2 barriers/step instead of 3.
//  * Matvec: 4 accumulator chains of 4 (was 2x8) for shorter MFMA dep chains.
//  * s_sleep(1) backoff after a failed poll check to cut coherence-point slam.
__global__ __launch_bounds__(256, 1) void k_lstm(
    const float* __restrict__ Whh_f, const float* __restrict__ Whh_b,
    const float* __restrict__ bih_f, const float* __restrict__ bhh_f,
    const float* __restrict__ bih_b, const float* __restrict__ bhh_b,
    const float* __restrict__ xg_f, const float* __restrict__ xg_b,
    unsigned* __restrict__ hbuf, float* __restrict__ enc)
{
  const int dir = blockIdx.x >> 5;
  const int w   = blockIdx.x & 31;
  const int tid = threadIdx.x;
  const int wave = tid >> 6, lane = tid & 63;
  const int col = lane & 15, quad = lane >> 4;

  const float* Whh = dir ? Whh_b : Whh_f;
  const float* xg  = dir ? xg_b  : xg_f;

  // ---- A-frag preload: wave 'wave' = gate, rows rowA = gate*512 + w*16 + col
  const int rowA = wave*H_DIM + w*16 + col;
  short8x w_frag[16];
  #pragma unroll
  for (int s=0;s<16;s++){
    const float* bp = Whh + (size_t)rowA*H_DIM + s*32 + quad*8;
    uint4 u = pack8(bp);
    w_frag[s] = *reinterpret_cast<short8x*>(&u);
  }

  // ---- wave-0 per-gate-value state (tid<64): bias, xg pipeline
  float bias_r = 0.f, xg_prev = 0.f, c_reg = 0.f;
  int row2 = 0;
  if (tid < 64){
    row2 = (tid >> 4)*H_DIM + w*16 + (tid & 15);
    bias_r = dir ? (bih_b[row2] + bhh_b[row2]) : (bih_f[row2] + bhh_f[row2]);
  }

  __shared__ __align__(16) unsigned short lds_hb[512];  // h_{t-1} as bf16
  __shared__ __align__(16) float raw[64];               // gate pre-activations

  unsigned* hb = hbuf + dir*1024;  // [2][512]

  // own h_0 = 0 staged locally (pollers never touch the own-WG range)
  if (tid < 16) lds_hb[w*16 + tid] = 0;

  // poller role: waves 2,3 -> thread p in [0,128), 4 consecutive words each;
  // the 4 threads whose words fall in the own-WG 16-word range are excluded.
  const int p = tid - 128;
  const bool is_poller = (wave >= 2) && ((p >> 2) != w);

  for (int t = 1; t <= T_LEN; ++t){
    const int tp = t - 1;                 // step being finished / tag wanted
    // ================= phase 1: gates+publish (wave0) ∥ poll (waves 2,3) =====
    if (tid < 64){
      if (t > 1){
        float v = raw[tid] + bias_r + xg_prev;
        const float va = ((tid >> 4) == 2) ? ftanh(v) : sigm(v);
        const int l2 = tid & 15;
        const float iv = __shfl(va, l2);
        const float fv = __shfl(va, l2 + 16);
        const float gg = __shfl(va, l2 + 32);
        const float ov = __shfl(va, l2 + 48);
        if (tid < 16){
          c_reg = fv*c_reg + iv*gg;
          const float hh = ov*ftanh(c_reg);
          const int hj = w*16 + tid;
          const unsigned short hbv = f2b(hh);
          // publish FIRST (remote WGs wait on this)
          __hip_atomic_store(hb + (tp&1)*512 + hj, ((unsigned)tp << 16) | (unsigned)hbv,
                             __ATOMIC_RELAXED, __HIP_MEMORY_SCOPE_AGENT);
          lds_hb[hj] = hbv;               // own fast path, no round trip
          const int tt = dir ? (T_LEN - tp) : (tp - 1);
          enc[(size_t)tt*D_DIM + dir*H_DIM + hj] = hh;
        }
      }
      // prefetch xg row t-1 (consumed by gates of step t, next iteration)
      xg_prev = xg[(size_t)(t-1)*G4 + row2];
    } else if (is_poller){
      unsigned* s0 = hb + (tp&1)*512 + p*4;
      const unsigned want = (unsigned)tp;
      unsigned v0, v1, v2, v3;
      for (;;){
        v0 = __hip_atomic_load(s0+0, __ATOMIC_RELAXED, __HIP_MEMORY_SCOPE_AGENT);
        v1 = __hip_atomic_load(s0+1, __ATOMIC_RELAXED, __HIP_MEMORY_SCOPE_AGENT);
        v2 = __hip_atomic_load(s0+2, __ATOMIC_RELAXED, __HIP_MEMORY_SCOPE_AGENT);
        v3 = __hip_atomic_load(s0+3, __ATOMIC_RELAXED, __HIP_MEMORY_SCOPE_AGENT);
        if (((v0>>16)==want) & ((v1>>16)==want) & ((v2>>16)==want) & ((v3>>16)==want)) break;
        __builtin_amdgcn_s_sleep(1);      // ~64cy backoff: cut L3 slam
      }
      uint2 pk;
      pk.x = (v0 & 0xffffu) | (v1 << 16);
      pk.y = (v2 & 0xffffu) | (v3 << 16);
      *reinterpret_cast<uint2*>(lds_hb + p*4) = pk;
    }
    __syncthreads();  // A: lds_hb = h_{t-1} fully staged

    // ================= matvec: 16 MFMAs, 4 chains of 4 =======================
    f32x4 a0 = (f32x4){0.f,0.f,0.f,0.f}, a1 = (f32x4){0.f,0.f,0.f,0.f};
    f32x4 a2 = (f32x4){0.f,0.f,0.f,0.f}, a3 = (f32x4){0.f,0.f,0.f,0.f};
    #pragma unroll
    for (int s=0;s<16;s+=4){
      const short8x b0 = *(const short8x*)(lds_hb + (s+0)*32 + quad*8);
      const short8x b1 = *(const short8x*)(lds_hb + (s+1)*32 + quad*8);
      const short8x b2 = *(const short8x*)(lds_hb + (s+2)*32 + quad*8);
      const short8x b3 = *(const short8x*)(lds_hb + (s+3)*32 + quad*8);
      a0 = __builtin_amdgcn_mfma_f32_16x16x32_bf16(w_frag[s+0], b0, a0, 0, 0, 0);
      a1 = __builtin_amdgcn_mfma_f32_16x16x32_bf16(w_frag[s+1], b1, a1, 0, 0, 0);
      a2 = __builtin_amdgcn_mfma_f32_16x16x32_bf16(w_frag[s+2], b2, a2, 0, 0, 0);
      a3 = __builtin_amdgcn_mfma_f32_16x16x32_bf16(w_frag[s+3], b3, a3, 0, 0, 0);
    }
    if (col == 0){
      f32x4 asum = (a0 + a1) + (a2 + a3);  // D[m], m = quad*4+i (all cols equal)
      *reinterpret_cast<f32x4*>(raw + wave*16 + quad*4) = asum;
    }
    __syncthreads();  // B: raw ready (consumed by gates next iteration)
  }

  // ---- epilogue: gates for step T_LEN (enc write only, no publish) ----------
  if (tid < 64){
    float v = raw[tid] + bias_r + xg_prev;
    const float va = ((tid >> 4) == 2) ? ftanh(v) : sigm(v);
    const int l2 = tid & 15;
    const float iv = __shfl(va, l2);
    const float fv = __shfl(va, l2 + 16);
    const float gg = __shfl(va, l2 + 32);
    const float ov = __shfl(va, l2 + 48);
    if (tid < 16){
      c_reg = fv*c_reg + iv*gg;
      const float hh = ov*ftanh(c_reg);
      const int hj = w*16 + tid;
      const int tt = dir ? 0 : (T_LEN - 1);
      enc[(size_t)tt*D_DIM + dir*H_DIM + hj] = hh;
    }
  }
}

// ---------------- row softmax in place, rows of 1024 --------------------------
__global__ __launch_bounds__(256) void k_softmax(float* __restrict__ S){
  float* r = S + (size_t)blockIdx.x*1024;
  const int tid = threadIdx.x;
  float v[4];
  #pragma unroll
  for (int i=0;i<4;i++) v[i] = r[tid + i*256];
  float m = fmaxf(fmaxf(v[0],v[1]), fmaxf(v[2],v[3]));
  #pragma unroll
  for (int off=32; off>=1; off>>=1) m = fmaxf(m, __shfl_xor(m, off));
  __shared__ float red[4], red2[4];
  const int wid = tid >> 6, lane = tid & 63;
  if (lane == 0) red[wid] = m;
  __syncthreads();
  m = fmaxf(fmaxf(red[0],red[1]), fmaxf(red[2],red[3]));
  float s = 0.f;
  #pragma unroll
  for (int i=0;i<4;i++){ v[i] = __expf(v[i]-m); s += v[i]; }
  #pragma unroll
  for (int off=32; off>=1; off>>=1) s += __shfl_xor(s, off);
  if (lane == 0) red2[wid] = s;
  __syncthreads();
  s = red2[0]+red2[1]+red2[2]+red2[3];
  const float inv = frcp(s);
  #pragma unroll
  for (int i=0;i<4;i++) r[tid + i*256] = v[i]*inv;
}

// ---------------- copy enc into cat[:, 0:1024] (f32) --------------------------
__global__ void k_copy_enc(const float* __restrict__ enc, float* __restrict__ cat){
  int idx = blockIdx.x*256 + threadIdx.x;
  if (idx < T_LEN*D_DIM){
    int t = idx >> 10, d = idx & 1023;
    cat[(size_t)t*2048 + d] = enc[idx];
  }
}

// ---------------- transpose-cast: encT_bf16[d][t] = bf16(enc[t][d]) -----------
__global__ __launch_bounds__(256) void k_castT(const float* __restrict__ src,
                                               unsigned short* __restrict__ dst){
  __shared__ float tile[32][33];
  const int bx = blockIdx.x*32, by = blockIdx.y*32;
  const int tx = threadIdx.x & 31, ty8 = threadIdx.x >> 5;
  #pragma unroll
  for (int i=ty8;i<32;i+=8) tile[i][tx] = src[(size_t)(by+i)*1024 + bx+tx];
  __syncthreads();
  #pragma unroll
  for (int i=ty8;i<32;i+=8) dst[(size_t)(bx+i)*1024 + by+tx] = f2b(tile[tx][i]);
}

// ---------------- feats = h1 * tag_W^T + tag_b  [1024,12] ---------------------
__global__ __launch_bounds__(256) void k_feats(
    const float* __restrict__ h1, const float* __restrict__ tagW,
    const float* __restrict__ tagb, float* __restrict__ feats)
{
  const int t = blockIdx.x;
  const int wave = threadIdx.x >> 6, lane = threadIdx.x & 63;
  const float* hr = h1 + (size_t)t*D_DIM;
  float hv[16];
  #pragma unroll
  for (int i=0;i<16;i++) hv[i] = hr[lane + 64*i];
  #pragma unroll
  for (int j=0;j<3;j++){
    const int tag = wave*3 + j;
    const float* wr = tagW + (size_t)tag*D_DIM;
    float s = 0.f;
    #pragma unroll
    for (int i=0;i<16;i++) s += hv[i]*wr[lane + 64*i];
    #pragma unroll
    for (int off=32; off>=1; off>>=1) s += __shfl_xor(s, off);
    if (lane == 0) feats[(size_t)t*K_TAGS + tag] = s + tagb[tag];
  }
}

// ---------------- CRF forward + gold score, single wave -----------------------
__global__ void k_crf(const float* __restrict__ feats, const float* __restrict__ trans,
                      const int* __restrict__ tags, float* __restrict__ out){
  const int tid = threadIdx.x;  // 64 threads, one wave
  float gold = 0.f;
  for (int i = tid; i <= T_LEN; i += 64){
    const int to = (i < T_LEN) ? tags[i]   : 11;        // STOP
    const int fr = (i == 0)    ? 10        : tags[i-1]; // START
    gold += trans[to*K_TAGS + fr];
    if (i < T_LEN) gold += feats[(size_t)i*K_TAGS + tags[i]];
  }
  #pragma unroll
  for (int off=32; off>=1; off>>=1) gold += __shfl_xor(gold, off);

  float Trow[K_TAGS];
  if (tid < K_TAGS){
    #pragma unroll
    for (int j=0;j<K_TAGS;j++) Trow[j] = trans[tid*K_TAGS + j];
  }
  float alpha = (tid == 10) ? 0.f : -10000.f;
  for (int t=0;t<T_LEN;++t){
    float av[K_TAGS];
    #pragma unroll
    for (int j=0;j<K_TAGS;j++) av[j] = __shfl(alpha, j);
    if (tid < K_TAGS){
      float vv[K_TAGS], m = -1e30f;
      #pragma unroll
      for (int j=0;j<K_TAGS;j++){ vv[j] = av[j] + Trow[j]; m = fmaxf(m, vv[j]); }
      float s = 0.f;
      #pragma unroll
      for (int j=0;j<K_TAGS;j++) s += __expf(vv[j]-m);
      alpha = m + __logf(s) + feats[(size_t)t*K_TAGS + tid];
    }
  }
  float v = (tid < K_TAGS) ? (alpha + trans[11*K_TAGS + tid]) : -1e30f;
  float m = v;
  #pragma unroll
  for (int off=32; off>=1; off>>=1) m = fmaxf(m, __shfl_xor(m, off));
  float e = (tid < K_TAGS) ? __expf(v - m) : 0.f;
  #pragma unroll
  for (int off=32; off>=1; off>>=1) e += __shfl_xor(e, off);
  if (tid == 0) out[0] = (m + __logf(e)) - gold;
}

// ------------------------------------------------------------------------------
extern "C" void kernel_launch(void* const* d_in, const int* in_sizes, int n_in,
                              void* d_out, int out_size, void* d_ws, size_t ws_size,
                              hipStream_t stream)
{
  const int*   sentence = (const int*)d_in[0];
  const int*   tags     = (const int*)d_in[1];
  const float* we       = (const float*)d_in[2];
  const float* Wih_f    = (const float*)d_in[3];
  const float* Whh_f    = (const float*)d_in[4];
  const float* bih_f    = (const float*)d_in[5];
  const float* bhh_f    = (const float*)d_in[6];
  const float* Wih_b    = (const float*)d_in[7];
  const float* Whh_b    = (const float*)d_in[8];
  const float* bih_b    = (const float*)d_in[9];
  const float* bhh_b    = (const float*)d_in[10];
  const float* attn_W   = (const float*)d_in[11];
  const float* attn_b   = (const float*)d_in[12];
  const float* h2h1_W   = (const float*)d_in[13];
  const float* h2h1_b   = (const float*)d_in[14];
  const float* tag_W    = (const float*)d_in[15];
  const float* tag_b    = (const float*)d_in[16];
  const float* trans    = (const float*)d_in[17];
  float* out = (float*)d_out;

  // workspace layout (floats) — identical footprint to the proven pool
  float* ws     = (float*)d_ws;
  float* cat    = ws;                  // [1024,2048]   also xg_f
  float* reg2   = cat  + 2097152;      // [2M]          xg_b; later scores+h1
  float* enc    = reg2 + 2097152;      // [1024,1024]
  float* proj   = enc  + 1048576;      // [1024,1024]   also x; later encT_bf16
  float* feats  = proj + 1048576;      // [1024,12]
  unsigned* hbuf= (unsigned*)(feats + 12288);  // 2048 u32
  float* xg_f   = cat;
  float* xg_b   = reg2;
  float* scores = reg2;
  float* h1     = reg2 + 1048576;
  float* x      = proj;
  unsigned short* encT = (unsigned short*)proj;  // 2 MiB, used after proj dead

  // 1. gather embeddings
  k_gather<<<dim3((T_LEN*E_DIM + 255)/256), dim3(256), 0, stream>>>(sentence, we, x);
  // 2. init h ring buffer
  k_init<<<dim3(8), dim3(256), 0, stream>>>(hbuf);
  // 3. xg_f = x * Wih_f^T        [1024,2048], K=300 ragged
  k_gemm_mfma<<<dim3(32,16), dim3(256), 0, stream>>>(x, E_DIM, 0,
      Wih_f, nullptr, E_DIM, nullptr, 0, xg_f, G4, T_LEN, G4, E_DIM);
  // 4. xg_b = rev(x) * Wih_b^T   [1024,2048]
  k_gemm_mfma<<<dim3(32,16), dim3(256), 0, stream>>>(x, E_DIM, 1,
      Wih_b, nullptr, E_DIM, nullptr, 0, xg_b, G4, T_LEN, G4, E_DIM);
  // 5. bidirectional recurrence -> enc [1024,1024]  (MFMA matvec, 64 WGs)
  k_lstm<<<dim3(64), dim3(256), 0, stream>>>(Whh_f, Whh_b, bih_f, bhh_f,
      bih_b, bhh_b, xg_f, xg_b, hbuf, enc);
  // 6. proj = enc * attn_W^T + attn_b
  k_gemm_mfma<<<dim3(16,16), dim3(256), 0, stream>>>(enc, D_DIM, 0,
      attn_W, nullptr, D_DIM, attn_b, 0, proj, D_DIM, T_LEN, D_DIM, D_DIM);
  // 7. scores = enc * proj^T
  k_gemm_mfma<<<dim3(16,16), dim3(256), 0, stream>>>(enc, D_DIM, 0,
      proj, nullptr, D_DIM, nullptr, 0, scores, T_LEN, T_LEN, T_LEN, D_DIM);
  // 8. row softmax in place
  k_softmax<<<dim3(1024), dim3(256), 0, stream>>>(scores);
  // 9. cat[:, :1024] = enc   (f32)
  k_copy_enc<<<dim3(4096), dim3(256), 0, stream>>>(enc, cat);
  // 10. encT_bf16 = enc^T    (proj region is dead now)
  k_castT<<<dim3(32,32), dim3(256), 0, stream>>>(enc, encT);
  // 11. cat[:, 1024:] = w * enc  via A=w, B=encT (bf16 precast)
  k_gemm_mfma<<<dim3(16,16), dim3(256), 0, stream>>>(scores, T_LEN, 0,
      nullptr, encT, D_DIM, nullptr, 0, cat + 1024, 2048, T_LEN, D_DIM, T_LEN);
  // 12. h1 = tanh(cat * h2h1_W^T + h2h1_b), K=2048
  k_gemm_mfma<<<dim3(16,16), dim3(256), 0, stream>>>(cat, 2048, 0,
      h2h1_W, nullptr, 2048, h2h1_b, 1, h1, D_DIM, T_LEN, D_DIM, 2048);
  // 13. feats = h1 * tag_W^T + tag_b   [1024,12]
  k_feats<<<dim3(1024), dim3(256), 0, stream>>>(h1, tag_W, tag_b, feats);
  // 14. CRF NLL
  k_crf<<<dim3(1), dim3(64), 0, stream>>>(feats, trans, tags, out);
}

// Round 4
// 1859.377 us; speedup vs baseline: 1.2754x; 1.2505x over previous
//
#include <hip/hip_runtime.h>
#include <hip/hip_fp16.h>

#define T_LEN 1024
#define E_DIM 300
#define H_DIM 512
#define D_DIM 1024
#define K_TAGS 12
#define G4 2048   // 4*H

typedef __attribute__((ext_vector_type(8))) short short8x;  // 8 bf16
typedef __attribute__((ext_vector_type(4))) float f32x4;

static __device__ __forceinline__ float frcp(float x){ return __builtin_amdgcn_rcpf(x); }
static __device__ __forceinline__ float sigm(float x){ return frcp(1.f + __expf(-x)); }
// overflow-safe fast tanh
static __device__ __forceinline__ float ftanh(float x){
  const float e = __expf(2.f * fabsf(x));
  const float t = 1.f - 2.f * frcp(e + 1.f);
  return copysignf(t, x);
}
// f32 -> bf16 round-to-nearest-even
static __device__ __forceinline__ unsigned short f2b(float f){
  unsigned u = __float_as_uint(f);
  return (unsigned short)((u + 0x7fffu + ((u >> 16) & 1u)) >> 16);
}
static __device__ __forceinline__ uint4 pack8(const float* s){
  uint4 o;
  o.x = (unsigned)f2b(s[0]) | ((unsigned)f2b(s[1]) << 16);
  o.y = (unsigned)f2b(s[2]) | ((unsigned)f2b(s[3]) << 16);
  o.z = (unsigned)f2b(s[4]) | ((unsigned)f2b(s[5]) << 16);
  o.w = (unsigned)f2b(s[6]) | ((unsigned)f2b(s[7]) << 16);
  return o;
}

// ---------------- gather: x[t,e] = word_embeds[sentence[t], e] ----------------
__global__ void k_gather(const int* __restrict__ sent, const float* __restrict__ we,
                         float* __restrict__ x){
  int idx = blockIdx.x*256 + threadIdx.x;
  if (idx < T_LEN*E_DIM){
    int t = idx / E_DIM, e = idx - t*E_DIM;
    x[idx] = we[(size_t)sent[t]*E_DIM + e];
  }
}

// ---------------- zero the tagged h ring buffer (2 dir * 2 slot * 512 u32) ----
__global__ void k_init(unsigned* __restrict__ hbuf){
  int i = blockIdx.x*256 + threadIdx.x;
  if (i < 2048) hbuf[i] = 0u;  // tag 0, bf16 value +0.0
}

// ---------------- MFMA bf16 GEMM: C = act( A(·rev?) * B^T + bias ) ------------
// (unchanged — verified)
__global__ __launch_bounds__(256) void k_gemm_mfma(
    const float* __restrict__ Af, int lda, int arev,
    const float* __restrict__ Bf, const unsigned short* __restrict__ Bh, int ldb,
    const float* __restrict__ bias, int act,
    float* __restrict__ C, int ldc, int M, int N, int K)
{
  __shared__ __align__(16) unsigned short As[64*40];
  __shared__ __align__(16) unsigned short Bs[64*40];
  const int tid = threadIdx.x;
  const int bm = blockIdx.y*64, bn = blockIdx.x*64;
  const int r  = tid >> 2, c8 = (tid & 3) * 8;
  const int wave = tid >> 6, lane = tid & 63;
  const int wm = (wave >> 1) * 32, wn = (wave & 1) * 32;
  const int col = lane & 15, quad = lane >> 4;

  const int am = arev ? (M-1-(bm+r)) : (bm+r);
  const float* arow = Af + (size_t)am*lda;
  const float* brow = Bf ? (Bf + (size_t)(bn+r)*ldb) : (const float*)0;
  const unsigned short* brh = Bh ? (Bh + (size_t)(bn+r)*ldb) : (const unsigned short*)0;

  uint4* aw = (uint4*)(As + r*40 + c8);
  uint4* bw = (uint4*)(Bs + r*40 + c8);

  f32x4 acc[2][2];
  #pragma unroll
  for (int i=0;i<2;i++)
    #pragma unroll
    for (int j=0;j<2;j++) acc[i][j] = (f32x4){0.f,0.f,0.f,0.f};

  for (int k0 = 0; k0 < K; k0 += 32){
    uint4 avv, bvv;
    if (k0 + 32 <= K){
      avv = pack8(arow + k0 + c8);
      bvv = Bh ? *(const uint4*)(brh + k0 + c8) : pack8(brow + k0 + c8);
    } else {
      float ta[8], tb[8];
      #pragma unroll
      for (int i=0;i<8;i++){
        const int kk = k0 + c8 + i;
        ta[i] = (kk < K) ? arow[kk] : 0.f;
        tb[i] = (kk < K && Bf) ? brow[kk] : 0.f;
      }
      avv = pack8(ta); bvv = pack8(tb);
    }
    if (k0) __syncthreads();
    *aw = avv; *bw = bvv;
    __syncthreads();
    const short8x a0 = *(const short8x*)(As + (wm+col)*40    + quad*8);
    const short8x a1 = *(const short8x*)(As + (wm+16+col)*40 + quad*8);
    const short8x b0 = *(const short8x*)(Bs + (wn+col)*40    + quad*8);
    const short8x b1 = *(const short8x*)(Bs + (wn+16+col)*40 + quad*8);
    acc[0][0] = __builtin_amdgcn_mfma_f32_16x16x32_bf16(a0, b0, acc[0][0], 0, 0, 0);
    acc[0][1] = __builtin_amdgcn_mfma_f32_16x16x32_bf16(a0, b1, acc[0][1], 0, 0, 0);
    acc[1][0] = __builtin_amdgcn_mfma_f32_16x16x32_bf16(a1, b0, acc[1][0], 0, 0, 0);
    acc[1][1] = __builtin_amdgcn_mfma_f32_16x16x32_bf16(a1, b1, acc[1][1], 0, 0, 0);
  }

  #pragma unroll
  for (int mt=0;mt<2;mt++){
    #pragma unroll
    for (int nt=0;nt<2;nt++){
      const int cc = bn + wn + 16*nt + col;
      const float bs = bias ? bias[cc] : 0.f;
      #pragma unroll
      for (int i=0;i<4;i++){
        const int rr = bm + wm + 16*mt + quad*4 + i;
        float v = acc[mt][nt][i] + bs;
        if (act) v = ftanh(v);
        C[(size_t)rr*ldc + cc] = v;
      }
    }
  }
}

// ---------------- persistent bidirectional LSTM recurrence (MFMA) -------------
// EXACT round-0 structure (1392 us verified): 256-thread poll, 2 words each,
// per-thread exit, 3 barriers, xg prefetch after the stage barrier.
// Single retained change from rounds 1-2 (proven correctness-neutral there):
// h published as (tag<<16)|bf16, so post-arrival staging is a mask instead of
// an f16->f32->bf16 VALU chain.
__global__ __launch_bounds__(256, 1) void k_lstm(
    const float* __restrict__ Whh_f, const float* __restrict__ Whh_b,
    const float* __restrict__ bih_f, const float* __restrict__ bhh_f,
    const float* __restrict__ bih_b, const float* __restrict__ bhh_b,
    const float* __restrict__ xg_f, const float* __restrict__ xg_b,
    unsigned* __restrict__ hbuf, float* __restrict__ enc)
{
  const int dir = blockIdx.x >> 5;
  const int w   = blockIdx.x & 31;
  const int tid = threadIdx.x;
  const int wave = tid >> 6, lane = tid & 63;
  const int col = lane & 15, quad = lane >> 4;

  const float* Whh = dir ? Whh_b : Whh_f;
  const float* xg  = dir ? xg_b  : xg_f;

  // ---- A-frag preload: wave 'wave' = gate, rows rowA = gate*512 + w*16 + col
  const int rowA = wave*H_DIM + w*16 + col;
  short8x w_frag[16];
  #pragma unroll
  for (int s=0;s<16;s++){
    const float* bp = Whh + (size_t)rowA*H_DIM + s*32 + quad*8;
    uint4 u = pack8(bp);
    w_frag[s] = *reinterpret_cast<short8x*>(&u);
  }

  // ---- wave-0 per-gate-value state (tid<64): bias, xg pipeline
  float bias_r = 0.f, xg_cur = 0.f, c_reg = 0.f;
  int row2 = 0;
  if (tid < 64){
    row2 = (tid >> 4)*H_DIM + w*16 + (tid & 15);
    bias_r = dir ? (bih_b[row2] + bhh_b[row2]) : (bih_f[row2] + bhh_f[row2]);
    xg_cur = xg[row2];              // step t=1 uses xg row 0
  }

  __shared__ __align__(16) unsigned short lds_hb[512];  // h_{t-1} as bf16
  __shared__ __align__(16) float raw[64];               // gate pre-activations

  unsigned* hb = hbuf + dir*1024;  // [2][512]

  for (int t = 1; t <= T_LEN; ++t){
    // ---- stage h_{t-1}: poll 2 tagged words/thread, mask bf16 into LDS
    {
      unsigned* s0 = hb + ((t-1)&1)*512 + tid;
      const unsigned want = (unsigned)(t-1);
      unsigned v0 = __hip_atomic_load(s0,     __ATOMIC_RELAXED, __HIP_MEMORY_SCOPE_AGENT);
      unsigned v1 = __hip_atomic_load(s0+256, __ATOMIC_RELAXED, __HIP_MEMORY_SCOPE_AGENT);
      while (((v0 >> 16) != want) || ((v1 >> 16) != want)){
        v0 = __hip_atomic_load(s0,     __ATOMIC_RELAXED, __HIP_MEMORY_SCOPE_AGENT);
        v1 = __hip_atomic_load(s0+256, __ATOMIC_RELAXED, __HIP_MEMORY_SCOPE_AGENT);
      }
      lds_hb[tid]     = (unsigned short)(v0 & 0xffffu);
      lds_hb[tid+256] = (unsigned short)(v1 & 0xffffu);
    }
    __syncthreads();

    // prefetch next step's xg (consumed next iteration; ~1 step of cover)
    float xg_nxt = 0.f;
    if (tid < 64 && t < T_LEN) xg_nxt = xg[(size_t)t*G4 + row2];

    // ---- matvec: 16 chained-by-2 MFMAs, B = h broadcast-replicated
    f32x4 a0 = (f32x4){0.f,0.f,0.f,0.f}, a1 = (f32x4){0.f,0.f,0.f,0.f};
    #pragma unroll
    for (int s=0;s<16;s+=2){
      const short8x b0 = *(const short8x*)(lds_hb + s*32     + quad*8);
      const short8x b1 = *(const short8x*)(lds_hb + (s+1)*32 + quad*8);
      a0 = __builtin_amdgcn_mfma_f32_16x16x32_bf16(w_frag[s],   b0, a0, 0, 0, 0);
      a1 = __builtin_amdgcn_mfma_f32_16x16x32_bf16(w_frag[s+1], b1, a1, 0, 0, 0);
    }
    if (col == 0){
      f32x4 asum = a0 + a1;   // D[m] in regs i: m = quad*4+i (same for all cols)
      *reinterpret_cast<f32x4*>(raw + wave*16 + quad*4) = asum;
    }
    __syncthreads();

    // ---- gates + state update, all inside wave 0 (shfl handoff, no barrier)
    if (tid < 64){
      float v = raw[tid] + bias_r + xg_cur;
      const float va = ((tid >> 4) == 2) ? ftanh(v) : sigm(v);
      const int l2 = tid & 15;
      const float iv = __shfl(va, l2);
      const float fv = __shfl(va, l2 + 16);
      const float gg = __shfl(va, l2 + 32);
      const float ov = __shfl(va, l2 + 48);
      if (tid < 16){
        c_reg = fv*c_reg + iv*gg;
        const float hh = ov*ftanh(c_reg);
        const int hj = w*16 + tid;
        // publish FIRST (what other WGs wait on) — bf16 payload
        const unsigned hv = ((unsigned)t << 16) | (unsigned)f2b(hh);
        __hip_atomic_store(hb + (t&1)*512 + hj, hv,
                           __ATOMIC_RELAXED, __HIP_MEMORY_SCOPE_AGENT);
        const int tt = dir ? (T_LEN - t) : (t - 1);
        enc[(size_t)tt*D_DIM + dir*H_DIM + hj] = hh;
      }
      xg_cur = xg_nxt;
    }
    __syncthreads();  // protect lds_hb / raw reuse next iteration
  }
}

// ---------------- row softmax in place, rows of 1024 --------------------------
__global__ __launch_bounds__(256) void k_softmax(float* __restrict__ S){
  float* r = S + (size_t)blockIdx.x*1024;
  const int tid = threadIdx.x;
  float v[4];
  #pragma unroll
  for (int i=0;i<4;i++) v[i] = r[tid + i*256];
  float m = fmaxf(fmaxf(v[0],v[1]), fmaxf(v[2],v[3]));
  #pragma unroll
  for (int off=32; off>=1; off>>=1) m = fmaxf(m, __shfl_xor(m, off));
  __shared__ float red[4], red2[4];
  const int wid = tid >> 6, lane = tid & 63;
  if (lane == 0) red[wid] = m;
  __syncthreads();
  m = fmaxf(fmaxf(red[0],red[1]), fmaxf(red[2],red[3]));
  float s = 0.f;
  #pragma unroll
  for (int i=0;i<4;i++){ v[i] = __expf(v[i]-m); s += v[i]; }
  #pragma unroll
  for (int off=32; off>=1; off>>=1) s += __shfl_xor(s, off);
  if (lane == 0) red2[wid] = s;
  __syncthreads();
  s = red2[0]+red2[1]+red2[2]+red2[3];
  const float inv = frcp(s);
  #pragma unroll
  for (int i=0;i<4;i++) r[tid + i*256] = v[i]*inv;
}

// ---------------- copy enc into cat[:, 0:1024] (f32) --------------------------
__global__ void k_copy_enc(const float* __restrict__ enc, float* __restrict__ cat){
  int idx = blockIdx.x*256 + threadIdx.x;
  if (idx < T_LEN*D_DIM){
    int t = idx >> 10, d = idx & 1023;
    cat[(size_t)t*2048 + d] = enc[idx];
  }
}

// ---------------- transpose-cast: encT_bf16[d][t] = bf16(enc[t][d]) -----------
__global__ __launch_bounds__(256) void k_castT(const float* __restrict__ src,
                                               unsigned short* __restrict__ dst){
  __shared__ float tile[32][33];
  const int bx = blockIdx.x*32, by = blockIdx.y*32;
  const int tx = threadIdx.x & 31, ty8 = threadIdx.x >> 5;
  #pragma unroll
  for (int i=ty8;i<32;i+=8) tile[i][tx] = src[(size_t)(by+i)*1024 + bx+tx];
  __syncthreads();
  #pragma unroll
  for (int i=ty8;i<32;i+=8) dst[(size_t)(bx+i)*1024 + by+tx] = f2b(tile[tx][i]);
}

// ---------------- feats = h1 * tag_W^T + tag_b  [1024,12] ---------------------
__global__ __launch_bounds__(256) void k_feats(
    const float* __restrict__ h1, const float* __restrict__ tagW,
    const float* __restrict__ tagb, float* __restrict__ feats)
{
  const int t = blockIdx.x;
  const int wave = threadIdx.x >> 6, lane = threadIdx.x & 63;
  const float* hr = h1 + (size_t)t*D_DIM;
  float hv[16];
  #pragma unroll
  for (int i=0;i<16;i++) hv[i] = hr[lane + 64*i];
  #pragma unroll
  for (int j=0;j<3;j++){
    const int tag = wave*3 + j;
    const float* wr = tagW + (size_t)tag*D_DIM;
    float s = 0.f;
    #pragma unroll
    for (int i=0;i<16;i++) s += hv[i]*wr[lane + 64*i];
    #pragma unroll
    for (int off=32; off>=1; off>>=1) s += __shfl_xor(s, off);
    if (lane == 0) feats[(size_t)t*K_TAGS + tag] = s + tagb[tag];
  }
}

// ---------------- CRF phase 1: 64 chunk products in the (LSE,+) semiring ------
// A_t[i][j] = trans[i][j] + feat_t[i]. alpha_T = (A_1023 (x) ... (x) A_0) (x) a0.
// Chunk c (one WG, lanes 0..11 active; lane r holds column r of M in regs):
//   M = A_{16c}; for s=1..15: M <- A_{16c+s} (x) M
//   M'[i][r] = feat[i] + LSE_k(trans[i][k] + M[k][r])     (no cross-lane needed)
__global__ __launch_bounds__(64) void k_crf1(const float* __restrict__ feats,
                                             const float* __restrict__ trans,
                                             float* __restrict__ chunkM){
  const int c = blockIdx.x;      // 0..63
  const int r = threadIdx.x;     // lane; active r<12
  __shared__ float sT[144];
  __shared__ float sF[16*12];
  for (int i=r; i<144; i+=64) sT[i] = trans[i];
  const int t0 = c*16;
  for (int i=r; i<192; i+=64) sF[i] = feats[(size_t)t0*K_TAGS + i];
  __syncthreads();
  if (r < 12){
    float m[12], nm[12];
    #pragma unroll
    for (int k=0;k<12;k++) m[k] = sT[k*12 + r] + sF[k];   // A_{t0} column r
    for (int s=1; s<16; ++s){
      #pragma unroll
      for (int i=0;i<12;i++){
        float v[12]; float mx = -1e30f;
        #pragma unroll
        for (int k=0;k<12;k++){ v[k] = sT[i*12+k] + m[k]; mx = fmaxf(mx, v[k]); }
        float ss = 0.f;
        #pragma unroll
        for (int k=0;k<12;k++) ss += __expf(v[k]-mx);
        nm[i] = sF[s*12+i] + mx + __logf(ss);
      }
      #pragma unroll
      for (int i=0;i<12;i++) m[i] = nm[i];
    }
    #pragma unroll
    for (int k=0;k<12;k++) chunkM[c*144 + k*12 + r] = m[k];
  }
}

// ---------------- CRF phase 2: 64-step alpha chain + gold + output ------------
// wave 0: alpha = M_63 (x) ... (x) M_0 (x) alpha0 (lane i holds alpha[i]),
//         with next-chunk register prefetch to hide L2 latency.
// wave 1: gold path score, in parallel.
__global__ __launch_bounds__(128) void k_crf2(const float* __restrict__ chunkM,
                                              const float* __restrict__ feats,
                                              const float* __restrict__ trans,
                                              const int* __restrict__ tags,
                                              float* __restrict__ out){
  const int tid = threadIdx.x, wave = tid >> 6, lane = tid & 63;
  __shared__ float sGold;
  float alpha = (lane == 10) ? 0.f : -10000.f;
  if (wave == 1){
    float g = 0.f;
    for (int i = lane; i <= T_LEN; i += 64){
      const int to = (i < T_LEN) ? tags[i]   : 11;        // STOP
      const int fr = (i == 0)    ? 10        : tags[i-1]; // START
      g += trans[to*K_TAGS + fr];
      if (i < T_LEN) g += feats[(size_t)i*K_TAGS + tags[i]];
    }
    #pragma unroll
    for (int off=32; off>=1; off>>=1) g += __shfl_xor(g, off);
    if (lane == 0) sGold = g;
  } else {
    float pf[12];
    #pragma unroll
    for (int k=0;k<12;k++) pf[k] = (lane < 12) ? chunkM[lane*12 + k] : 0.f;
    for (int c=0; c<64; ++c){
      float av[12];
      #pragma unroll
      for (int j=0;j<12;j++) av[j] = __shfl(alpha, j);
      float cur[12];
      #pragma unroll
      for (int k=0;k<12;k++) cur[k] = pf[k];
      if (c+1 < 64){
        #pragma unroll
        for (int k=0;k<12;k++)
          pf[k] = (lane < 12) ? chunkM[(c+1)*144 + lane*12 + k] : 0.f;
      }
      if (lane < 12){
        float v[12]; float mx = -1e30f;
        #pragma unroll
        for (int k=0;k<12;k++){ v[k] = cur[k] + av[k]; mx = fmaxf(mx, v[k]); }
        float ss = 0.f;
        #pragma unroll
        for (int k=0;k<12;k++) ss += __expf(v[k]-mx);
        alpha = mx + __logf(ss);
      }
    }
  }
  __syncthreads();
  if (wave == 0){
    float v = (lane < K_TAGS) ? (alpha + trans[11*K_TAGS + lane]) : -1e30f;
    float m = v;
    #pragma unroll
    for (int off=32; off>=1; off>>=1) m = fmaxf(m, __shfl_xor(m, off));
    float e = (lane < K_TAGS) ? __expf(v - m) : 0.f;
    #pragma unroll
    for (int off=32; off>=1; off>>=1) e += __shfl_xor(e, off);
    if (lane == 0) out[0] = (m + __logf(e)) - sGold;
  }
}

// ------------------------------------------------------------------------------
extern "C" void kernel_launch(void* const* d_in, const int* in_sizes, int n_in,
                              void* d_out, int out_size, void* d_ws, size_t ws_size,
                              hipStream_t stream)
{
  const int*   sentence = (const int*)d_in[0];
  const int*   tags     = (const int*)d_in[1];
  const float* we       = (const float*)d_in[2];
  const float* Wih_f    = (const float*)d_in[3];
  const float* Whh_f    = (const float*)d_in[4];
  const float* bih_f    = (const float*)d_in[5];
  const float* bhh_f    = (const float*)d_in[6];
  const float* Wih_b    = (const float*)d_in[7];
  const float* Whh_b    = (const float*)d_in[8];
  const float* bih_b    = (const float*)d_in[9];
  const float* bhh_b    = (const float*)d_in[10];
  const float* attn_W   = (const float*)d_in[11];
  const float* attn_b   = (const float*)d_in[12];
  const float* h2h1_W   = (const float*)d_in[13];
  const float* h2h1_b   = (const float*)d_in[14];
  const float* tag_W    = (const float*)d_in[15];
  const float* tag_b    = (const float*)d_in[16];
  const float* trans    = (const float*)d_in[17];
  float* out = (float*)d_out;

  // workspace layout (floats) — identical footprint to the proven pool
  float* ws     = (float*)d_ws;
  float* cat    = ws;                  // [1024,2048]   also xg_f
  float* reg2   = cat  + 2097152;      // [2M]          xg_b; later scores+h1
  float* enc    = reg2 + 2097152;      // [1024,1024]
  float* proj   = enc  + 1048576;      // [1024,1024]   also x; later encT_bf16 + chunkM
  float* feats  = proj + 1048576;      // [1024,12]
  unsigned* hbuf= (unsigned*)(feats + 12288);  // 2048 u32
  float* xg_f   = cat;
  float* xg_b   = reg2;
  float* scores = reg2;
  float* h1     = reg2 + 1048576;
  float* x      = proj;
  unsigned short* encT = (unsigned short*)proj;  // 2 MiB, used after proj dead
  float* chunkM = proj + 524288;       // 36 KiB, used after encT's GEMM (step 11)

  // 1. gather embeddings
  k_gather<<<dim3((T_LEN*E_DIM + 255)/256), dim3(256), 0, stream>>>(sentence, we, x);
  // 2. init h ring buffer
  k_init<<<dim3(8), dim3(256), 0, stream>>>(hbuf);
  // 3. xg_f = x * Wih_f^T        [1024,2048], K=300 ragged
  k_gemm_mfma<<<dim3(32,16), dim3(256), 0, stream>>>(x, E_DIM, 0,
      Wih_f, nullptr, E_DIM, nullptr, 0, xg_f, G4, T_LEN, G4, E_DIM);
  // 4. xg_b = rev(x) * Wih_b^T   [1024,2048]
  k_gemm_mfma<<<dim3(32,16), dim3(256), 0, stream>>>(x, E_DIM, 1,
      Wih_b, nullptr, E_DIM, nullptr, 0, xg_b, G4, T_LEN, G4, E_DIM);
  // 5. bidirectional recurrence -> enc [1024,1024]  (MFMA matvec, 64 WGs)
  k_lstm<<<dim3(64), dim3(256), 0, stream>>>(Whh_f, Whh_b, bih_f, bhh_f,
      bih_b, bhh_b, xg_f, xg_b, hbuf, enc);
  // 6. proj = enc * attn_W^T + attn_b
  k_gemm_mfma<<<dim3(16,16), dim3(256), 0, stream>>>(enc, D_DIM, 0,
      attn_W, nullptr, D_DIM, attn_b, 0, proj, D_DIM, T_LEN, D_DIM, D_DIM);
  // 7. scores = enc * proj^T
  k_gemm_mfma<<<dim3(16,16), dim3(256), 0, stream>>>(enc, D_DIM, 0,
      proj, nullptr, D_DIM, nullptr, 0, scores, T_LEN, T_LEN, T_LEN, D_DIM);
  // 8. row softmax in place
  k_softmax<<<dim3(1024), dim3(256), 0, stream>>>(scores);
  // 9. cat[:, :1024] = enc   (f32)
  k_copy_enc<<<dim3(4096), dim3(256), 0, stream>>>(enc, cat);
  // 10. encT_bf16 = enc^T    (proj region is dead now)
  k_castT<<<dim3(32,32), dim3(256), 0, stream>>>(enc, encT);
  // 11. cat[:, 1024:] = w * enc  via A=w, B=encT (bf16 precast)
  k_gemm_mfma<<<dim3(16,16), dim3(256), 0, stream>>>(scores, T_LEN, 0,
      nullptr, encT, D_DIM, nullptr, 0, cat + 1024, 2048, T_LEN, D_DIM, T_LEN);
  // 12. h1 = tanh(cat * h2h1_W^T + h2h1_b), K=2048
  k_gemm_mfma<<<dim3(16,16), dim3(256), 0, stream>>>(cat, 2048, 0,
      h2h1_W, nullptr, 2048, h2h1_b, 1, h1, D_DIM, T_LEN, D_DIM, 2048);
  // 13. feats = h1 * tag_W^T + tag_b   [1024,12]
  k_feats<<<dim3(1024), dim3(256), 0, stream>>>(h1, tag_W, tag_b, feats);
  // 14. CRF NLL: 64 parallel chunk products, then 64-step chain + gold
  k_crf1<<<dim3(64), dim3(64), 0, stream>>>(feats, trans, chunkM);
  k_crf2<<<dim3(1), dim3(128), 0, stream>>>(chunkM, feats, trans, tags, out);
}

// Round 5
// 1790.045 us; speedup vs baseline: 1.3248x; 1.0387x over previous
//
#include <hip/hip_runtime.h>
#include <hip/hip_fp16.h>

#define T_LEN 1024
#define E_DIM 300
#define H_DIM 512
#define D_DIM 1024
#define K_TAGS 12
#define G4 2048   // 4*H

typedef __attribute__((ext_vector_type(8))) short short8x;  // 8 bf16
typedef __attribute__((ext_vector_type(4))) float f32x4;

static __device__ __forceinline__ float frcp(float x){ return __builtin_amdgcn_rcpf(x); }
static __device__ __forceinline__ float sigm(float x){ return frcp(1.f + __expf(-x)); }
// overflow-safe fast tanh
static __device__ __forceinline__ float ftanh(float x){
  const float e = __expf(2.f * fabsf(x));
  const float t = 1.f - 2.f * frcp(e + 1.f);
  return copysignf(t, x);
}
// f32 -> bf16 round-to-nearest-even
static __device__ __forceinline__ unsigned short f2b(float f){
  unsigned u = __float_as_uint(f);
  return (unsigned short)((u + 0x7fffu + ((u >> 16) & 1u)) >> 16);
}
static __device__ __forceinline__ uint4 pack8(const float* s){
  uint4 o;
  o.x = (unsigned)f2b(s[0]) | ((unsigned)f2b(s[1]) << 16);
  o.y = (unsigned)f2b(s[2]) | ((unsigned)f2b(s[3]) << 16);
  o.z = (unsigned)f2b(s[4]) | ((unsigned)f2b(s[5]) << 16);
  o.w = (unsigned)f2b(s[6]) | ((unsigned)f2b(s[7]) << 16);
  return o;
}
static __device__ __forceinline__ uint4 pack8u(const unsigned short* s){
  uint4 o;
  o.x = (unsigned)s[0] | ((unsigned)s[1] << 16);
  o.y = (unsigned)s[2] | ((unsigned)s[3] << 16);
  o.z = (unsigned)s[4] | ((unsigned)s[5] << 16);
  o.w = (unsigned)s[6] | ((unsigned)s[7] << 16);
  return o;
}

// ---------------- gather: xh[t,e] = bf16(word_embeds[sentence[t], e]) ---------
__global__ void k_gather(const int* __restrict__ sent, const float* __restrict__ we,
                         unsigned short* __restrict__ xh){
  int idx = blockIdx.x*256 + threadIdx.x;
  if (idx < T_LEN*E_DIM){
    int t = idx / E_DIM, e = idx - t*E_DIM;
    xh[idx] = f2b(we[(size_t)sent[t]*E_DIM + e]);
  }
}

// ---------------- generic vectorized f32 -> bf16 cast (n multiple of 4) -------
__global__ __launch_bounds__(256) void k_cast(const float* __restrict__ src,
                                              unsigned short* __restrict__ dst,
                                              int n4){
  int i = blockIdx.x*256 + threadIdx.x;
  if (i < n4){
    const float4 v = *reinterpret_cast<const float4*>(src + (size_t)i*4);
    ushort2 a, b;
    a.x = f2b(v.x); a.y = f2b(v.y); b.x = f2b(v.z); b.y = f2b(v.w);
    *reinterpret_cast<ushort2*>(dst + (size_t)i*4)     = a;
    *reinterpret_cast<ushort2*>(dst + (size_t)i*4 + 2) = b;
  }
}

// ---------------- zero the tagged h ring buffer (2 dir * 2 slot * 512 u32) ----
__global__ void k_init(unsigned* __restrict__ hbuf){
  int i = blockIdx.x*256 + threadIdx.x;
  if (i < 2048) hbuf[i] = 0u;  // tag 0, bf16 value +0.0
}

// ---------------- MFMA bf16 GEMM: C = act( A(·rev?) * B^T + bias ) ------------
// Round-5: pure-bf16 operands (all inputs precast once), C stored f32 or bf16.
// Staging is now a plain uint4 global->LDS copy (was ~100 VALU f2b ops/iter).
__global__ __launch_bounds__(256) void k_gemm_mfma(
    const unsigned short* __restrict__ Ah, int lda, int arev,
    const unsigned short* __restrict__ Bh, int ldb,
    const float* __restrict__ bias, int act,
    void* __restrict__ Cp, int ldc, int cbf16, int M, int N, int K)
{
  __shared__ __align__(16) unsigned short As[64*40];
  __shared__ __align__(16) unsigned short Bs[64*40];
  const int tid = threadIdx.x;
  const int bm = blockIdx.y*64, bn = blockIdx.x*64;
  const int r  = tid >> 2, c8 = (tid & 3) * 8;
  const int wave = tid >> 6, lane = tid & 63;
  const int wm = (wave >> 1) * 32, wn = (wave & 1) * 32;
  const int col = lane & 15, quad = lane >> 4;

  const int am = arev ? (M-1-(bm+r)) : (bm+r);
  const unsigned short* arow = Ah + (size_t)am*lda;
  const unsigned short* brow = Bh + (size_t)(bn+r)*ldb;

  uint4* aw = (uint4*)(As + r*40 + c8);
  uint4* bw = (uint4*)(Bs + r*40 + c8);

  f32x4 acc[2][2];
  #pragma unroll
  for (int i=0;i<2;i++)
    #pragma unroll
    for (int j=0;j<2;j++) acc[i][j] = (f32x4){0.f,0.f,0.f,0.f};

  for (int k0 = 0; k0 < K; k0 += 32){
    uint4 avv, bvv;
    if (k0 + 32 <= K){
      avv = *(const uint4*)(arow + k0 + c8);
      bvv = *(const uint4*)(brow + k0 + c8);
    } else {
      unsigned short ta[8], tb[8];
      #pragma unroll
      for (int i=0;i<8;i++){
        const int kk = k0 + c8 + i;
        ta[i] = (kk < K) ? arow[kk] : (unsigned short)0;
        tb[i] = (kk < K) ? brow[kk] : (unsigned short)0;
      }
      avv = pack8u(ta); bvv = pack8u(tb);
    }
    if (k0) __syncthreads();
    *aw = avv; *bw = bvv;
    __syncthreads();
    const short8x a0 = *(const short8x*)(As + (wm+col)*40    + quad*8);
    const short8x a1 = *(const short8x*)(As + (wm+16+col)*40 + quad*8);
    const short8x b0 = *(const short8x*)(Bs + (wn+col)*40    + quad*8);
    const short8x b1 = *(const short8x*)(Bs + (wn+16+col)*40 + quad*8);
    acc[0][0] = __builtin_amdgcn_mfma_f32_16x16x32_bf16(a0, b0, acc[0][0], 0, 0, 0);
    acc[0][1] = __builtin_amdgcn_mfma_f32_16x16x32_bf16(a0, b1, acc[0][1], 0, 0, 0);
    acc[1][0] = __builtin_amdgcn_mfma_f32_16x16x32_bf16(a1, b0, acc[1][0], 0, 0, 0);
    acc[1][1] = __builtin_amdgcn_mfma_f32_16x16x32_bf16(a1, b1, acc[1][1], 0, 0, 0);
  }

  #pragma unroll
  for (int mt=0;mt<2;mt++){
    #pragma unroll
    for (int nt=0;nt<2;nt++){
      const int cc = bn + wn + 16*nt + col;
      const float bs = bias ? bias[cc] : 0.f;
      #pragma unroll
      for (int i=0;i<4;i++){
        const int rr = bm + wm + 16*mt + quad*4 + i;
        float v = acc[mt][nt][i] + bs;
        if (act) v = ftanh(v);
        if (cbf16) ((unsigned short*)Cp)[(size_t)rr*ldc + cc] = f2b(v);
        else       ((float*)Cp)[(size_t)rr*ldc + cc] = v;
      }
    }
  }
}

// ---------------- persistent bidirectional LSTM recurrence (MFMA) -------------
// EXACT verified structure (1340 us, round-4): 256-thread poll, 2 words each,
// per-thread exit, 3 barriers, bf16 publish payload. DO NOT TOUCH.
__global__ __launch_bounds__(256, 1) void k_lstm(
    const float* __restrict__ Whh_f, const float* __restrict__ Whh_b,
    const float* __restrict__ bih_f, const float* __restrict__ bhh_f,
    const float* __restrict__ bih_b, const float* __restrict__ bhh_b,
    const float* __restrict__ xg_f, const float* __restrict__ xg_b,
    unsigned* __restrict__ hbuf, float* __restrict__ enc)
{
  const int dir = blockIdx.x >> 5;
  const int w   = blockIdx.x & 31;
  const int tid = threadIdx.x;
  const int wave = tid >> 6, lane = tid & 63;
  const int col = lane & 15, quad = lane >> 4;

  const float* Whh = dir ? Whh_b : Whh_f;
  const float* xg  = dir ? xg_b  : xg_f;

  // ---- A-frag preload: wave 'wave' = gate, rows rowA = gate*512 + w*16 + col
  const int rowA = wave*H_DIM + w*16 + col;
  short8x w_frag[16];
  #pragma unroll
  for (int s=0;s<16;s++){
    const float* bp = Whh + (size_t)rowA*H_DIM + s*32 + quad*8;
    uint4 u = pack8(bp);
    w_frag[s] = *reinterpret_cast<short8x*>(&u);
  }

  // ---- wave-0 per-gate-value state (tid<64): bias, xg pipeline
  float bias_r = 0.f, xg_cur = 0.f, c_reg = 0.f;
  int row2 = 0;
  if (tid < 64){
    row2 = (tid >> 4)*H_DIM + w*16 + (tid & 15);
    bias_r = dir ? (bih_b[row2] + bhh_b[row2]) : (bih_f[row2] + bhh_f[row2]);
    xg_cur = xg[row2];              // step t=1 uses xg row 0
  }

  __shared__ __align__(16) unsigned short lds_hb[512];  // h_{t-1} as bf16
  __shared__ __align__(16) float raw[64];               // gate pre-activations

  unsigned* hb = hbuf + dir*1024;  // [2][512]

  for (int t = 1; t <= T_LEN; ++t){
    // ---- stage h_{t-1}: poll 2 tagged words/thread, mask bf16 into LDS
    {
      unsigned* s0 = hb + ((t-1)&1)*512 + tid;
      const unsigned want = (unsigned)(t-1);
      unsigned v0 = __hip_atomic_load(s0,     __ATOMIC_RELAXED, __HIP_MEMORY_SCOPE_AGENT);
      unsigned v1 = __hip_atomic_load(s0+256, __ATOMIC_RELAXED, __HIP_MEMORY_SCOPE_AGENT);
      while (((v0 >> 16) != want) || ((v1 >> 16) != want)){
        v0 = __hip_atomic_load(s0,     __ATOMIC_RELAXED, __HIP_MEMORY_SCOPE_AGENT);
        v1 = __hip_atomic_load(s0+256, __ATOMIC_RELAXED, __HIP_MEMORY_SCOPE_AGENT);
      }
      lds_hb[tid]     = (unsigned short)(v0 & 0xffffu);
      lds_hb[tid+256] = (unsigned short)(v1 & 0xffffu);
    }
    __syncthreads();

    // prefetch next step's xg (consumed next iteration; ~1 step of cover)
    float xg_nxt = 0.f;
    if (tid < 64 && t < T_LEN) xg_nxt = xg[(size_t)t*G4 + row2];

    // ---- matvec: 16 chained-by-2 MFMAs, B = h broadcast-replicated
    f32x4 a0 = (f32x4){0.f,0.f,0.f,0.f}, a1 = (f32x4){0.f,0.f,0.f,0.f};
    #pragma unroll
    for (int s=0;s<16;s+=2){
      const short8x b0 = *(const short8x*)(lds_hb + s*32     + quad*8);
      const short8x b1 = *(const short8x*)(lds_hb + (s+1)*32 + quad*8);
      a0 = __builtin_amdgcn_mfma_f32_16x16x32_bf16(w_frag[s],   b0, a0, 0, 0, 0);
      a1 = __builtin_amdgcn_mfma_f32_16x16x32_bf16(w_frag[s+1], b1, a1, 0, 0, 0);
    }
    if (col == 0){
      f32x4 asum = a0 + a1;   // D[m] in regs i: m = quad*4+i (same for all cols)
      *reinterpret_cast<f32x4*>(raw + wave*16 + quad*4) = asum;
    }
    __syncthreads();

    // ---- gates + state update, all inside wave 0 (shfl handoff, no barrier)
    if (tid < 64){
      float v = raw[tid] + bias_r + xg_cur;
      const float va = ((tid >> 4) == 2) ? ftanh(v) : sigm(v);
      const int l2 = tid & 15;
      const float iv = __shfl(va, l2);
      const float fv = __shfl(va, l2 + 16);
      const float gg = __shfl(va, l2 + 32);
      const float ov = __shfl(va, l2 + 48);
      if (tid < 16){
        c_reg = fv*c_reg + iv*gg;
        const float hh = ov*ftanh(c_reg);
        const int hj = w*16 + tid;
        // publish FIRST (what other WGs wait on) — bf16 payload
        const unsigned hv = ((unsigned)t << 16) | (unsigned)f2b(hh);
        __hip_atomic_store(hb + (t&1)*512 + hj, hv,
                           __ATOMIC_RELAXED, __HIP_MEMORY_SCOPE_AGENT);
        const int tt = dir ? (T_LEN - t) : (t - 1);
        enc[(size_t)tt*D_DIM + dir*H_DIM + hj] = hh;
      }
      xg_cur = xg_nxt;
    }
    __syncthreads();  // protect lds_hb / raw reuse next iteration
  }
}

// ---------------- row softmax in place + bf16 copy, rows of 1024 --------------
__global__ __launch_bounds__(256) void k_softmax(float* __restrict__ S,
                                                 unsigned short* __restrict__ Sh){
  float* r = S + (size_t)blockIdx.x*1024;
  unsigned short* rh = Sh + (size_t)blockIdx.x*1024;
  const int tid = threadIdx.x;
  float v[4];
  #pragma unroll
  for (int i=0;i<4;i++) v[i] = r[tid + i*256];
  float m = fmaxf(fmaxf(v[0],v[1]), fmaxf(v[2],v[3]));
  #pragma unroll
  for (int off=32; off>=1; off>>=1) m = fmaxf(m, __shfl_xor(m, off));
  __shared__ float red[4], red2[4];
  const int wid = tid >> 6, lane = tid & 63;
  if (lane == 0) red[wid] = m;
  __syncthreads();
  m = fmaxf(fmaxf(red[0],red[1]), fmaxf(red[2],red[3]));
  float s = 0.f;
  #pragma unroll
  for (int i=0;i<4;i++){ v[i] = __expf(v[i]-m); s += v[i]; }
  #pragma unroll
  for (int off=32; off>=1; off>>=1) s += __shfl_xor(s, off);
  if (lane == 0) red2[wid] = s;
  __syncthreads();
  s = red2[0]+red2[1]+red2[2]+red2[3];
  const float inv = frcp(s);
  #pragma unroll
  for (int i=0;i<4;i++){
    const float o = v[i]*inv;
    r[tid + i*256]  = o;
    rh[tid + i*256] = f2b(o);
  }
}

// ---------------- cast enc into cath[:, 0:1024] (bf16) ------------------------
__global__ void k_copy_enc(const float* __restrict__ enc,
                           unsigned short* __restrict__ cath){
  int idx = blockIdx.x*256 + threadIdx.x;
  if (idx < T_LEN*D_DIM){
    int t = idx >> 10, d = idx & 1023;
    cath[(size_t)t*2048 + d] = f2b(enc[idx]);
  }
}

// ---------------- transpose-cast: encT_bf16[d][t] = bf16(enc[t][d]) -----------
__global__ __launch_bounds__(256) void k_castT(const float* __restrict__ src,
                                               unsigned short* __restrict__ dst){
  __shared__ float tile[32][33];
  const int bx = blockIdx.x*32, by = blockIdx.y*32;
  const int tx = threadIdx.x & 31, ty8 = threadIdx.x >> 5;
  #pragma unroll
  for (int i=ty8;i<32;i+=8) tile[i][tx] = src[(size_t)(by+i)*1024 + bx+tx];
  __syncthreads();
  #pragma unroll
  for (int i=ty8;i<32;i+=8) dst[(size_t)(bx+i)*1024 + by+tx] = f2b(tile[tx][i]);
}

// ---------------- feats = h1 * tag_W^T + tag_b  [1024,12] ---------------------
__global__ __launch_bounds__(256) void k_feats(
    const float* __restrict__ h1, const float* __restrict__ tagW,
    const float* __restrict__ tagb, float* __restrict__ feats)
{
  const int t = blockIdx.x;
  const int wave = threadIdx.x >> 6, lane = threadIdx.x & 63;
  const float* hr = h1 + (size_t)t*D_DIM;
  float hv[16];
  #pragma unroll
  for (int i=0;i<16;i++) hv[i] = hr[lane + 64*i];
  #pragma unroll
  for (int j=0;j<3;j++){
    const int tag = wave*3 + j;
    const float* wr = tagW + (size_t)tag*D_DIM;
    float s = 0.f;
    #pragma unroll
    for (int i=0;i<16;i++) s += hv[i]*wr[lane + 64*i];
    #pragma unroll
    for (int off=32; off>=1; off>>=1) s += __shfl_xor(s, off);
    if (lane == 0) feats[(size_t)t*K_TAGS + tag] = s + tagb[tag];
  }
}

// ---------------- CRF phase 1: 64 chunk products in the (LSE,+) semiring ------
__global__ __launch_bounds__(64) void k_crf1(const float* __restrict__ feats,
                                             const float* __restrict__ trans,
                                             float* __restrict__ chunkM){
  const int c = blockIdx.x;      // 0..63
  const int r = threadIdx.x;     // lane; active r<12
  __shared__ float sT[144];
  __shared__ float sF[16*12];
  for (int i=r; i<144; i+=64) sT[i] = trans[i];
  const int t0 = c*16;
  for (int i=r; i<192; i+=64) sF[i] = feats[(size_t)t0*K_TAGS + i];
  __syncthreads();
  if (r < 12){
    float m[12], nm[12];
    #pragma unroll
    for (int k=0;k<12;k++) m[k] = sT[k*12 + r] + sF[k];   // A_{t0} column r
    for (int s=1; s<16; ++s){
      #pragma unroll
      for (int i=0;i<12;i++){
        float v[12]; float mx = -1e30f;
        #pragma unroll
        for (int k=0;k<12;k++){ v[k] = sT[i*12+k] + m[k]; mx = fmaxf(mx, v[k]); }
        float ss = 0.f;
        #pragma unroll
        for (int k=0;k<12;k++) ss += __expf(v[k]-mx);
        nm[i] = sF[s*12+i] + mx + __logf(ss);
      }
      #pragma unroll
      for (int i=0;i<12;i++) m[i] = nm[i];
    }
    #pragma unroll
    for (int k=0;k<12;k++) chunkM[c*144 + k*12 + r] = m[k];
  }
}

// ---------------- CRF phase 2: 64-step alpha chain + gold + output ------------
__global__ __launch_bounds__(128) void k_crf2(const float* __restrict__ chunkM,
                                              const float* __restrict__ feats,
                                              const float* __restrict__ trans,
                                              const int* __restrict__ tags,
                                              float* __restrict__ out){
  const int tid = threadIdx.x, wave = tid >> 6, lane = tid & 63;
  __shared__ float sGold;
  float alpha = (lane == 10) ? 0.f : -10000.f;
  if (wave == 1){
    float g = 0.f;
    for (int i = lane; i <= T_LEN; i += 64){
      const int to = (i < T_LEN) ? tags[i]   : 11;        // STOP
      const int fr = (i == 0)    ? 10        : tags[i-1]; // START
      g += trans[to*K_TAGS + fr];
      if (i < T_LEN) g += feats[(size_t)i*K_TAGS + tags[i]];
    }
    #pragma unroll
    for (int off=32; off>=1; off>>=1) g += __shfl_xor(g, off);
    if (lane == 0) sGold = g;
  } else {
    float pf[12];
    #pragma unroll
    for (int k=0;k<12;k++) pf[k] = (lane < 12) ? chunkM[lane*12 + k] : 0.f;
    for (int c=0; c<64; ++c){
      float av[12];
      #pragma unroll
      for (int j=0;j<12;j++) av[j] = __shfl(alpha, j);
      float cur[12];
      #pragma unroll
      for (int k=0;k<12;k++) cur[k] = pf[k];
      if (c+1 < 64){
        #pragma unroll
        for (int k=0;k<12;k++)
          pf[k] = (lane < 12) ? chunkM[(c+1)*144 + lane*12 + k] : 0.f;
      }
      if (lane < 12){
        float v[12]; float mx = -1e30f;
        #pragma unroll
        for (int k=0;k<12;k++){ v[k] = cur[k] + av[k]; mx = fmaxf(mx, v[k]); }
        float ss = 0.f;
        #pragma unroll
        for (int k=0;k<12;k++) ss += __expf(v[k]-mx);
        alpha = mx + __logf(ss);
      }
    }
  }
  __syncthreads();
  if (wave == 0){
    float v = (lane < K_TAGS) ? (alpha + trans[11*K_TAGS + lane]) : -1e30f;
    float m = v;
    #pragma unroll
    for (int off=32; off>=1; off>>=1) m = fmaxf(m, __shfl_xor(m, off));
    float e = (lane < K_TAGS) ? __expf(v - m) : 0.f;
    #pragma unroll
    for (int off=32; off>=1; off>>=1) e += __shfl_xor(e, off);
    if (lane == 0) out[0] = (m + __logf(e)) - sGold;
  }
}

// ------------------------------------------------------------------------------
extern "C" void kernel_launch(void* const* d_in, const int* in_sizes, int n_in,
                              void* d_out, int out_size, void* d_ws, size_t ws_size,
                              hipStream_t stream)
{
  const int*   sentence = (const int*)d_in[0];
  const int*   tags     = (const int*)d_in[1];
  const float* we       = (const float*)d_in[2];
  const float* Wih_f    = (const float*)d_in[3];
  const float* Whh_f    = (const float*)d_in[4];
  const float* bih_f    = (const float*)d_in[5];
  const float* bhh_f    = (const float*)d_in[6];
  const float* Wih_b    = (const float*)d_in[7];
  const float* Whh_b    = (const float*)d_in[8];
  const float* bih_b    = (const float*)d_in[9];
  const float* bhh_b    = (const float*)d_in[10];
  const float* attn_W   = (const float*)d_in[11];
  const float* attn_b   = (const float*)d_in[12];
  const float* h2h1_W   = (const float*)d_in[13];
  const float* h2h1_b   = (const float*)d_in[14];
  const float* tag_W    = (const float*)d_in[15];
  const float* tag_b    = (const float*)d_in[16];
  const float* trans    = (const float*)d_in[17];
  float* out = (float*)d_out;

  // ---- workspace layout: identical 24 MB footprint, lifetime-aliased --------
  float* ws = (float*)d_ws;
  float* R1 = ws;                    // 2097152 f32 (8 MB)
  float* R2 = ws + 2097152;          // 2097152 f32 (8 MB)
  float* R3 = ws + 4194304;          // 1048576 f32 (4 MB)
  float* R4 = ws + 5242880;          // 1048576 f32 (4 MB)
  float* feats = ws + 6291456;       // 12288 f32
  unsigned* hbuf = (unsigned*)(ws + 6303744);  // 2048 u32

  // pre-lstm phase
  float* xg_f = R1;                                        // 8 MB f32
  float* xg_b = R2;                                        // 8 MB f32
  float* enc  = R3;                                        // 4 MB f32
  unsigned short* xh      = (unsigned short*)R4;           // 1024*300
  unsigned short* Wih_fh  = (unsigned short*)R4 + 307200;  // 2048*300
  unsigned short* Wih_bh  = (unsigned short*)R4 + 921600;  // 2048*300 (3 MB total)
  // post-lstm phase (xg_f/xg_b/xh/Wih_* dead)
  unsigned short* cath    = (unsigned short*)R1;           // [1024][2048] bf16 (4 MB)
  unsigned short* attn_Wh = (unsigned short*)(R1 + 1048576); // 1024*1024 (2 MB)
  unsigned short* h2h1_Wh = (unsigned short*)R2;           // 1024*2048 (4 MB)
  float* scores = R2 + 1048576;                            // [1024][1024] f32 (4 MB)
  unsigned short* encT    = (unsigned short*)R4;           // [1024][1024] bf16 (2 MB)
  unsigned short* projh   = (unsigned short*)R4 + 1048576; // [1024][1024] bf16 (2 MB)
  unsigned short* scoresh = (unsigned short*)R3;           // 2 MB (enc dead after castT)
  float* h1     = R3;                                      // 4 MB f32 (scoresh dead)
  float* chunkM = R4;                                      // 36 KB (encT dead after GEMM11)

  // 1. gather embeddings -> bf16
  k_gather<<<dim3((T_LEN*E_DIM + 255)/256), dim3(256), 0, stream>>>(sentence, we, xh);
  // 2. init h ring buffer
  k_init<<<dim3(8), dim3(256), 0, stream>>>(hbuf);
  // 3a/3b. precast LSTM input weights
  k_cast<<<dim3(600),  dim3(256), 0, stream>>>(Wih_f, Wih_fh, 153600);
  k_cast<<<dim3(600),  dim3(256), 0, stream>>>(Wih_b, Wih_bh, 153600);
  // 4. xg_f = x * Wih_f^T ; xg_b = rev(x) * Wih_b^T   [1024,2048], K=300 ragged
  k_gemm_mfma<<<dim3(32,16), dim3(256), 0, stream>>>(xh, E_DIM, 0,
      Wih_fh, E_DIM, nullptr, 0, xg_f, G4, 0, T_LEN, G4, E_DIM);
  k_gemm_mfma<<<dim3(32,16), dim3(256), 0, stream>>>(xh, E_DIM, 1,
      Wih_bh, E_DIM, nullptr, 0, xg_b, G4, 0, T_LEN, G4, E_DIM);
  // 5. bidirectional recurrence -> enc [1024,1024]  (MFMA matvec, 64 WGs)
  k_lstm<<<dim3(64), dim3(256), 0, stream>>>(Whh_f, Whh_b, bih_f, bhh_f,
      bih_b, bhh_b, xg_f, xg_b, hbuf, enc);
  // 6. cath[:, :1024] = bf16(enc); encT = bf16(enc^T); precast attn/h2h1 weights
  k_copy_enc<<<dim3(4096), dim3(256), 0, stream>>>(enc, cath);
  k_castT<<<dim3(32,32), dim3(256), 0, stream>>>(enc, encT);
  k_cast<<<dim3(1024), dim3(256), 0, stream>>>(attn_W, attn_Wh, 262144);
  k_cast<<<dim3(2048), dim3(256), 0, stream>>>(h2h1_W, h2h1_Wh, 524288);
  // 7. projh = bf16(enc * attn_W^T + attn_b)
  k_gemm_mfma<<<dim3(16,16), dim3(256), 0, stream>>>(cath, 2048, 0,
      attn_Wh, D_DIM, attn_b, 0, projh, D_DIM, 1, T_LEN, D_DIM, D_DIM);
  // 8. scores = enc * proj^T   (f32)
  k_gemm_mfma<<<dim3(16,16), dim3(256), 0, stream>>>(cath, 2048, 0,
      projh, D_DIM, nullptr, 0, scores, T_LEN, 0, T_LEN, T_LEN, D_DIM);
  // 9. row softmax in place + bf16 copy
  k_softmax<<<dim3(1024), dim3(256), 0, stream>>>(scores, scoresh);
  // 10. cath[:, 1024:] = bf16(w * enc)  via A=scoresh, B=encT
  k_gemm_mfma<<<dim3(16,16), dim3(256), 0, stream>>>(scoresh, T_LEN, 0,
      encT, D_DIM, nullptr, 0, cath + 1024, 2048, 1, T_LEN, D_DIM, T_LEN);
  // 11. h1 = tanh(cat * h2h1_W^T + h2h1_b), K=2048  (f32)
  k_gemm_mfma<<<dim3(16,16), dim3(256), 0, stream>>>(cath, 2048, 0,
      h2h1_Wh, 2048, h2h1_b, 1, h1, D_DIM, 0, T_LEN, D_DIM, 2048);
  // 12. feats = h1 * tag_W^T + tag_b   [1024,12]
  k_feats<<<dim3(1024), dim3(256), 0, stream>>>(h1, tag_W, tag_b, feats);
  // 13. CRF NLL: 64 parallel chunk products, then 64-step chain + gold
  k_crf1<<<dim3(64), dim3(64), 0, stream>>>(feats, trans, chunkM);
  k_crf2<<<dim3(1), dim3(128), 0, stream>>>(chunkM, feats, trans, tags, out);
}